// Round 8
// baseline (1378.489 us; speedup 1.0000x reference)
//
#include <hip/hip_runtime.h>
#include <math.h>

#define N_NODES 100000
#define N_EDGES 1200000
#define N_GRAPHS 16
#define CH 64
#define HEADS 4
#define GL 6
#define IN_DIM 261
#define GDIM 24
#define LIN 32
#define LL 3
#define EPSN 1e-5f
#define NPART 16           // moments partials
#define RNG (N_NODES / 8)  // 12500 nodes per dst-range

typedef unsigned short u16;
typedef __attribute__((ext_vector_type(8))) short bf16x8;
typedef __attribute__((ext_vector_type(4))) float f32x4;

__device__ __forceinline__ u16 f2bf(float f) {
  unsigned u = __float_as_uint(f);
  u = (u + 0x7FFFu + ((u >> 16) & 1u)) >> 16;
  return (u16)u;
}
__device__ __forceinline__ float bf2f(u16 v) {
  return __uint_as_float(((unsigned)v) << 16);
}

__device__ __forceinline__ float gelu_exact(float x) {
  return 0.5f * x * (1.0f + erff(x * 0.70710678118654752440f));
}

__device__ __forceinline__ float ln32(float x, float w, float b) {
  float m = x;
  m += __shfl_xor(m, 1); m += __shfl_xor(m, 2); m += __shfl_xor(m, 4);
  m += __shfl_xor(m, 8); m += __shfl_xor(m, 16);
  m *= (1.0f / 32.0f);
  float d = x - m;
  float v = d * d;
  v += __shfl_xor(v, 1); v += __shfl_xor(v, 2); v += __shfl_xor(v, 4);
  v += __shfl_xor(v, 8); v += __shfl_xor(v, 16);
  v *= (1.0f / 32.0f);
  return d * rsqrtf(v + EPSN) * w + b;
}

// ---------------- setup: CSR build, dst-range partitioned ----------------
__global__ void k_count_part(const int* __restrict__ dst, int* __restrict__ deg) {
  const int range = blockIdx.x & 7;
  const int sub = blockIdx.x >> 3;
  const int lo = range * RNG, hi = lo + RNG;
  for (int e = sub * 256 + threadIdx.x; e < N_EDGES; e += 256 * 256) {
    int d = dst[e];
    if (d >= lo && d < hi) atomicAdd(&deg[d], 1);
  }
}

__global__ void k_scatter_part(const int* __restrict__ src, const int* __restrict__ dst,
                               int* __restrict__ cur, int* __restrict__ ssrc) {
  const int range = blockIdx.x & 7;
  const int sub = blockIdx.x >> 3;
  const int lo = range * RNG, hi = lo + RNG;
  for (int e = sub * 256 + threadIdx.x; e < N_EDGES; e += 256 * 256) {
    int d = dst[e];
    if (d >= lo && d < hi) {
      int p = atomicAdd(&cur[d], 1);
      ssrc[p] = src[e];
    }
  }
}

__global__ void k_block_sums(const int* __restrict__ deg, int* __restrict__ bsum) {
  __shared__ int sh[256];
  int i = blockIdx.x * 256 + threadIdx.x;
  sh[threadIdx.x] = (i < N_NODES) ? deg[i] : 0;
  __syncthreads();
  for (int s = 128; s > 0; s >>= 1) {
    if (threadIdx.x < s) sh[threadIdx.x] += sh[threadIdx.x + s];
    __syncthreads();
  }
  if (threadIdx.x == 0) bsum[blockIdx.x] = sh[0];
}

__global__ void k_scan_bsums(int* __restrict__ bsum, int nb, int* __restrict__ off) {
  __shared__ int sh[512];
  int i = threadIdx.x;
  int v = (i < nb) ? bsum[i] : 0;
  sh[i] = v;
  __syncthreads();
  for (int s = 1; s < 512; s <<= 1) {
    int t = (i >= s) ? sh[i - s] : 0;
    __syncthreads();
    sh[i] += t;
    __syncthreads();
  }
  if (i < nb) bsum[i] = sh[i] - v;
  if (i == nb - 1) off[N_NODES] = sh[i];
}

__global__ void k_scan_final(const int* __restrict__ deg, const int* __restrict__ bsum,
                             int* __restrict__ off, int* __restrict__ cur) {
  __shared__ int sh[256];
  int i = blockIdx.x * 256 + threadIdx.x;
  int v = (i < N_NODES) ? deg[i] : 0;
  sh[threadIdx.x] = v;
  __syncthreads();
  for (int s = 1; s < 256; s <<= 1) {
    int t = (threadIdx.x >= s) ? sh[threadIdx.x - s] : 0;
    __syncthreads();
    sh[threadIdx.x] += t;
    __syncthreads();
  }
  if (i < N_NODES) {
    int ex = bsum[blockIdx.x] + sh[threadIdx.x] - v;
    off[i] = ex;
    cur[i] = ex;
  }
}

__global__ void k_graph_starts(const int* __restrict__ batch, int* __restrict__ gstart) {
  int g = threadIdx.x;
  if (g > N_GRAPHS) return;
  int lo = 0, hi = N_NODES;
  while (lo < hi) {
    int mid = (lo + hi) >> 1;
    if (batch[mid] < g) lo = mid + 1; else hi = mid;
  }
  gstart[g] = lo;
}

// ---------------- weight prep: fp32 -> bf16 B-fragment swizzle ----------------
#define W0S_ELEMS (4 * 9 * 64 * 8)
#define WGS_ELEMS (4 * 2 * 64 * 8)
__global__ void k_prep_w(const float* __restrict__ W0, const float* __restrict__ Wg,
                         u16* __restrict__ W0s, u16* __restrict__ Wgs) {
  int idx = blockIdx.x * 256 + threadIdx.x;
  if (idx < W0S_ELEMS) {
    int i = idx & 7, lane = (idx >> 3) & 63, ks = (idx >> 9) % 9, cb = idx / (9 * 512);
    int k = ks * 32 + (lane >> 4) * 8 + i, c = cb * 16 + (lane & 15);
    W0s[idx] = f2bf(k < IN_DIM ? W0[k * 64 + c] : 0.f);
  } else if (idx < W0S_ELEMS + GL * WGS_ELEMS) {
    int j = idx - W0S_ELEMS;
    int l = j / WGS_ELEMS, p = j % WGS_ELEMS;
    int i = p & 7, lane = (p >> 3) & 63, ks = (p >> 9) & 1, cb = p / (2 * 512);
    int k = ks * 32 + (lane >> 4) * 8 + i, c = cb * 16 + (lane & 15);
    Wgs[j] = f2bf(Wg[(size_t)l * 4096 + k * 64 + c]);
  }
}

// ---------------- per-layer: MFMA GEMM (T = X @ W, bf16) ----------------
template <int KS, bool F32IN>
__global__ __launch_bounds__(256) void k_gemm_mfma(
    const void* __restrict__ Xin, const u16* __restrict__ Wswz,
    u16* __restrict__ Tb) {
  const int lane = threadIdx.x & 63;
  const int wid = (blockIdx.x << 2) + (threadIdx.x >> 6);
  const int NT = N_NODES / 16;
  if (wid >= NT) return;
  const int grp = lane >> 4, n16 = lane & 15;
  const long r0 = (long)wid * 16;

  bf16x8 afr[KS];
  if constexpr (!F32IN) {
    const u16* xrow = (const u16*)Xin + (r0 + n16) * (KS * 32) + grp * 8;
    #pragma unroll
    for (int ks = 0; ks < KS; ++ks) afr[ks] = *(const bf16x8*)(xrow + ks * 32);
  } else {
    const float* xr = (const float*)Xin + (r0 + n16) * (size_t)IN_DIM;
    #pragma unroll
    for (int ks = 0; ks < KS; ++ks) {
      bf16x8 a;
      #pragma unroll
      for (int i = 0; i < 8; ++i) {
        int k = ks * 32 + grp * 8 + i;
        float v = (k < IN_DIM) ? xr[k] : 0.f;
        a[i] = (short)f2bf(v);
      }
      afr[ks] = a;
    }
  }

  #pragma unroll
  for (int cb = 0; cb < 4; ++cb) {
    f32x4 a = {0.f, 0.f, 0.f, 0.f};
    #pragma unroll
    for (int ks = 0; ks < KS; ++ks) {
      bf16x8 b = *(const bf16x8*)(Wswz + ((size_t)(cb * KS + ks) * 64 + lane) * 8);
      a = __builtin_amdgcn_mfma_f32_16x16x32_bf16(afr[ks], b, a, 0, 0, 0);
    }
    #pragma unroll
    for (int r = 0; r < 4; ++r)
      Tb[(r0 + grp * 4 + r) * 64 + cb * 16 + n16] = f2bf(a[r]);
  }
}

// ---------------- per-layer: edge softmax + aggregate (wave per node) ----------------
// Logits computed in-register from the gathered T rows (no ES/ED arrays, no random
// ES line fetches). Each 16-lane head group owns its head's logit via shfl_xor reduce.
__global__ __launch_bounds__(256) void k_edge_agg(
    const u16* __restrict__ Tb, const int* __restrict__ off, const int* __restrict__ ssrc,
    const float* __restrict__ a_src, const float* __restrict__ a_dst,
    const float* __restrict__ bias, float* __restrict__ F) {
  const int lane = threadIdx.x & 63;
  const int n = blockIdx.x * 4 + (threadIdx.x >> 6);
  if (n >= N_NODES) return;
  const int e0 = off[n];
  const int ec = off[n + 1] - e0;
  const float asl = a_src[lane];
  const float adl = a_dst[lane];
  const u16* Tl = Tb + lane;
  const float tself = bf2f(Tl[(long)n * 64]);
  // ed (dst term) and self-loop logit from own row, per 16-lane head group
  float ed = tself * adl;
  ed += __shfl_xor(ed, 1); ed += __shfl_xor(ed, 2); ed += __shfl_xor(ed, 4); ed += __shfl_xor(ed, 8);
  float es0 = tself * asl;
  es0 += __shfl_xor(es0, 1); es0 += __shfl_xor(es0, 2); es0 += __shfl_xor(es0, 4); es0 += __shfl_xor(es0, 8);
  float l0 = es0 + ed;
  l0 = fmaxf(l0, 0.2f * l0);
  const float p0 = __expf(fminf(l0, 30.f));
  float s_run = p0;
  float acc = p0 * tself;
  for (int base = 0; base < ec; base += 16) {
    const int ne = min(16, ec - base);
    const int sv = ssrc[e0 + min(base + (lane & 15), ec - 1)];
    int rows[16];
    #pragma unroll
    for (int e = 0; e < 16; ++e) rows[e] = __shfl(sv, e);
    float tv[16];
    #pragma unroll
    for (int e = 0; e < 16; ++e) tv[e] = bf2f(Tl[(long)rows[e] * 64]);
    #pragma unroll
    for (int e = 0; e < 16; ++e) {
      float pe = tv[e] * asl;
      pe += __shfl_xor(pe, 1); pe += __shfl_xor(pe, 2);
      pe += __shfl_xor(pe, 4); pe += __shfl_xor(pe, 8);
      float lg = pe + ed;
      lg = fmaxf(lg, 0.2f * lg);
      const float p = (e < ne) ? __expf(fminf(lg, 30.f)) : 0.f;
      s_run += p;
      acc = fmaf(p, tv[e], acc);
    }
  }
  const float o = acc / (s_run + 1e-16f) + bias[lane];
  F[(long)n * 64 + lane] = gelu_exact(o);
}

// ---------------- GraphNorm: moments + stats fused (last-block pattern) ----------------
__global__ void k_moments_stats(const float* __restrict__ F, const int* __restrict__ gstart,
                                const float* __restrict__ ms,
                                float* __restrict__ SP, float* __restrict__ SQP,
                                float* __restrict__ MM, float* __restrict__ IS,
                                int* __restrict__ cnt, int compute_stats) {
  const int g = blockIdx.x;
  const int s0 = gstart[g];
  const int rows = gstart[g + 1] - s0;
  const int lane = threadIdx.x & 63;
  const int w = threadIdx.x >> 6;
  float sum = 0.f, sq = 0.f;
  for (int r = blockIdx.y * 4 + w; r < rows; r += gridDim.y * 4) {
    float v = F[(long)(s0 + r) * 64 + lane];
    sum += v;
    sq = fmaf(v, v, sq);
  }
  __shared__ float ls[4][64];
  __shared__ float lq[4][64];
  __shared__ int lastdone;
  ls[w][lane] = sum;
  lq[w][lane] = sq;
  __syncthreads();
  if (threadIdx.x < 64) {
    float a = ls[0][lane] + ls[1][lane] + ls[2][lane] + ls[3][lane];
    float b = lq[0][lane] + lq[1][lane] + lq[2][lane] + lq[3][lane];
    SP[(blockIdx.y * N_GRAPHS + g) * 64 + lane] = a;
    SQP[(blockIdx.y * N_GRAPHS + g) * 64 + lane] = b;
    __threadfence();
  }
  __syncthreads();
  if (threadIdx.x == 0) {
    lastdone = 0;
    if (compute_stats) {
      int c = atomicAdd(cnt, 1);
      lastdone = (c == N_GRAPHS * NPART - 1) ? 1 : 0;
    }
  }
  __syncthreads();
  if (lastdone) {
    __threadfence();
    for (int i = threadIdx.x; i < N_GRAPHS * 64; i += blockDim.x) {
      int gg = i >> 6, c = i & 63;
      float s = 0.f, q = 0.f;
      #pragma unroll
      for (int b2 = 0; b2 < NPART; ++b2) {
        s += SP[(b2 * N_GRAPHS + gg) * 64 + c];
        q += SQP[(b2 * N_GRAPHS + gg) * 64 + c];
      }
      float cntf = fmaxf((float)(gstart[gg + 1] - gstart[gg]), 1.0f);
      float mean = s / cntf;
      float mm = mean * ms[c];
      float var = q / cntf - 2.f * mm * mean + mm * mm;
      MM[i] = mm;
      IS[i] = rsqrtf(fmaxf(var, 0.f) + EPSN);
    }
    if (threadIdx.x == 0) *cnt = 0;
  }
}

__global__ void k_norm_res(const float* __restrict__ F, const int* __restrict__ batch,
                           const float* __restrict__ MM, const float* __restrict__ IS,
                           const float* __restrict__ w, const float* __restrict__ b,
                           float* __restrict__ X, u16* __restrict__ Xb, int residual) {
  const long i4 = (long)blockIdx.x * 256 + threadIdx.x;
  const int n = (int)(i4 >> 4);
  const int c4 = (int)(i4 & 15) << 2;
  const int g = batch[n];
  float4 f = *(const float4*)(F + i4 * 4);
  float4 mm = *(const float4*)(MM + g * 64 + c4);
  float4 is = *(const float4*)(IS + g * 64 + c4);
  float4 wv = *(const float4*)(w + c4);
  float4 bv = *(const float4*)(b + c4);
  float4 y;
  y.x = fmaf(wv.x * (f.x - mm.x), is.x, bv.x);
  y.y = fmaf(wv.y * (f.y - mm.y), is.y, bv.y);
  y.z = fmaf(wv.z * (f.z - mm.z), is.z, bv.z);
  y.w = fmaf(wv.w * (f.w - mm.w), is.w, bv.w);
  float4* xp = (float4*)(X + i4 * 4);
  if (residual) {
    float4 xo = *xp;
    y.x += xo.x; y.y += xo.y; y.z += xo.z; y.w += xo.w;
  }
  *xp = y;
  union { u16 s[4]; unsigned long long ll; } pk;
  pk.s[0] = f2bf(y.x); pk.s[1] = f2bf(y.y); pk.s[2] = f2bf(y.z); pk.s[3] = f2bf(y.w);
  *(unsigned long long*)(Xb + i4 * 4) = pk.ll;
}

// ---------------- pooled MLP head (one block) ----------------
__global__ __launch_bounds__(512) void k_mlp(
    const float* __restrict__ SP, const int* __restrict__ gstart, const float* __restrict__ gf,
    const float* __restrict__ W0, const float* __restrict__ b0,
    const float* __restrict__ lw0, const float* __restrict__ lb0,
    const float* __restrict__ Wg, const float* __restrict__ bg,
    const float* __restrict__ lwg, const float* __restrict__ lbg,
    const float* __restrict__ hW, const float* __restrict__ hb,
    float* __restrict__ out) {
  __shared__ float P[16][88];
  __shared__ float Z[16][32];
  const int tid = threadIdx.x;
  for (int i = tid; i < 16 * 88; i += 512) {
    int g = i / 88, c = i - g * 88;
    float v;
    if (c < 64) {
      float s = 0.f;
      #pragma unroll
      for (int b = 0; b < NPART; ++b) s += SP[(b * N_GRAPHS + g) * 64 + c];
      float cnt = fmaxf((float)(gstart[g + 1] - gstart[g]), 1.0f);
      v = s / cnt;
    } else {
      v = gf[g * GDIM + (c - 64)];
    }
    P[g][c] = v;
  }
  __syncthreads();
  const int g = tid >> 5, c = tid & 31;
  float acc = b0[c];
  for (int k = 0; k < 88; ++k) acc = fmaf(P[g][k], W0[k * 32 + c], acc);
  float z = ln32(gelu_exact(acc), lw0[c], lb0[c]);
  for (int l = 0; l < LL; ++l) {
    Z[g][c] = z;
    __syncthreads();
    float a2 = bg[l * 32 + c];
    const float* Wl = Wg + l * 32 * 32;
    for (int k = 0; k < 32; ++k) a2 = fmaf(Z[g][k], Wl[k * 32 + c], a2);
    __syncthreads();
    z = ln32(gelu_exact(a2), lwg[l * 32 + c], lbg[l * 32 + c]) + z;
  }
  Z[g][c] = z * hW[c];
  __syncthreads();
  if (c == 0) {
    float s = 0.f;
    for (int k = 0; k < 32; ++k) s += Z[g][k];
    out[g] = s + hb[0];
  }
}

extern "C" void kernel_launch(void* const* d_in, const int* in_sizes, int n_in,
                              void* d_out, int out_size, void* d_ws, size_t ws_size,
                              hipStream_t stream) {
  const float* x   = (const float*)d_in[0];
  const int*   ei  = (const int*)d_in[1];
  const int* batch = (const int*)d_in[2];
  const float* gf  = (const float*)d_in[3];
  const float* W0  = (const float*)d_in[4];
  const float* as0 = (const float*)d_in[5];
  const float* ad0 = (const float*)d_in[6];
  const float* b0  = (const float*)d_in[7];
  const float* gw0 = (const float*)d_in[8];
  const float* gb0 = (const float*)d_in[9];
  const float* gm0 = (const float*)d_in[10];
  const float* Wg  = (const float*)d_in[11];
  const float* asg = (const float*)d_in[12];
  const float* adg = (const float*)d_in[13];
  const float* bg  = (const float*)d_in[14];
  const float* gwg = (const float*)d_in[15];
  const float* gbg = (const float*)d_in[16];
  const float* gmg = (const float*)d_in[17];
  const float* mW0 = (const float*)d_in[18];
  const float* mb0 = (const float*)d_in[19];
  const float* lw0 = (const float*)d_in[20];
  const float* lb0 = (const float*)d_in[21];
  const float* mWg = (const float*)d_in[22];
  const float* mbg = (const float*)d_in[23];
  const float* lwg = (const float*)d_in[24];
  const float* lbg = (const float*)d_in[25];
  const float* hW  = (const float*)d_in[26];
  const float* hb  = (const float*)d_in[27];
  float* out = (float*)d_out;
  const int* src = ei;
  const int* dst = ei + N_EDGES;

  char* p = (char*)d_ws;
  auto alloc = [&](size_t bytes) {
    char* r = p;
    p += (bytes + 255) & ~(size_t)255;
    return (void*)r;
  };
  float* X   = (float*)alloc((size_t)N_NODES * 64 * 4);
  float* F   = (float*)alloc((size_t)N_NODES * 64 * 4);
  u16*   Xb  = (u16*)alloc((size_t)N_NODES * 64 * 2);
  u16*   Tb  = (u16*)alloc((size_t)N_NODES * 64 * 2);
  int* ssrc  = (int*)alloc((size_t)N_EDGES * 4);
  int* deg   = (int*)alloc((size_t)N_NODES * 4);
  int* off   = (int*)alloc((size_t)(N_NODES + 1) * 4);
  int* cur   = (int*)alloc((size_t)N_NODES * 4);
  int* bsum  = (int*)alloc(4096);
  int* gstart = (int*)alloc((N_GRAPHS + 1) * 4);
  u16* W0s   = (u16*)alloc((size_t)W0S_ELEMS * 2);
  u16* Wgs   = (u16*)alloc((size_t)GL * WGS_ELEMS * 2);
  float* SP  = (float*)alloc(NPART * N_GRAPHS * 64 * 4);
  float* SQP = (float*)alloc(NPART * N_GRAPHS * 64 * 4);
  float* MM  = (float*)alloc(N_GRAPHS * 64 * 4);
  float* IS  = (float*)alloc(N_GRAPHS * 64 * 4);
  int* cnt   = (int*)alloc(256);
  (void)ws_size; (void)in_sizes; (void)n_in; (void)out_size;

  const int NB = (N_NODES + 255) / 256;
  hipMemsetAsync(deg, 0, (size_t)N_NODES * 4, stream);
  hipMemsetAsync(cnt, 0, 256, stream);
  k_count_part<<<2048, 256, 0, stream>>>(dst, deg);
  k_block_sums<<<NB, 256, 0, stream>>>(deg, bsum);
  k_scan_bsums<<<1, 512, 0, stream>>>(bsum, NB, off);
  k_scan_final<<<NB, 256, 0, stream>>>(deg, bsum, off, cur);
  k_scatter_part<<<2048, 256, 0, stream>>>(src, dst, cur, ssrc);
  k_graph_starts<<<1, 32, 0, stream>>>(batch, gstart);
  k_prep_w<<<(W0S_ELEMS + GL * WGS_ELEMS + 255) / 256, 256, 0, stream>>>(W0, Wg, W0s, Wgs);

  const int GG = (N_NODES / 16 + 3) / 4;
  for (int l = 0; l < 1 + GL; ++l) {
    const float* asl = (l == 0) ? as0 : (asg + (size_t)(l - 1) * 64);
    const float* adl = (l == 0) ? ad0 : (adg + (size_t)(l - 1) * 64);
    const float* bl  = (l == 0) ? b0  : (bg  + (size_t)(l - 1) * 64);
    const float* gwl = (l == 0) ? gw0 : (gwg + (size_t)(l - 1) * 64);
    const float* gbl = (l == 0) ? gb0 : (gbg + (size_t)(l - 1) * 64);
    const float* gml = (l == 0) ? gm0 : (gmg + (size_t)(l - 1) * 64);
    if (l == 0)
      k_gemm_mfma<9, true><<<GG, 256, 0, stream>>>(x, W0s, Tb);
    else
      k_gemm_mfma<2, false><<<GG, 256, 0, stream>>>(Xb, Wgs + (size_t)(l - 1) * WGS_ELEMS, Tb);
    k_edge_agg<<<N_NODES / 4, 256, 0, stream>>>(Tb, off, ssrc, asl, adl, bl, F);
    k_moments_stats<<<dim3(N_GRAPHS, NPART), 256, 0, stream>>>(F, gstart, gml, SP, SQP, MM, IS, cnt, 1);
    k_norm_res<<<(N_NODES * 64) / 1024, 256, 0, stream>>>(F, batch, MM, IS, gwl, gbl, X, Xb, l > 0);
  }

  k_moments_stats<<<dim3(N_GRAPHS, NPART), 256, 0, stream>>>(X, gstart, gm0, SP, SQP, MM, IS, cnt, 0);
  k_mlp<<<1, 512, 0, stream>>>(SP, gstart, gf, mW0, mb0, lw0, lb0,
                               mWg, mbg, lwg, lbg, hW, hb, out);
}

// Round 9
// 988.766 us; speedup vs baseline: 1.3942x; 1.3942x over previous
//
#include <hip/hip_runtime.h>
#include <math.h>

#define N_NODES 100000
#define N_EDGES 1200000
#define N_GRAPHS 16
#define CH 64
#define HEADS 4
#define GL 6
#define IN_DIM 261
#define GDIM 24
#define LIN 32
#define LL 3
#define EPSN 1e-5f
#define NPART 16           // moments partials
#define RNG (N_NODES / 8)  // 12500 nodes per dst-range

typedef unsigned short u16;
typedef __attribute__((ext_vector_type(8))) short bf16x8;
typedef __attribute__((ext_vector_type(4))) float f32x4;

__device__ __forceinline__ u16 f2bf(float f) {
  unsigned u = __float_as_uint(f);
  u = (u + 0x7FFFu + ((u >> 16) & 1u)) >> 16;
  return (u16)u;
}
__device__ __forceinline__ float bf2f(u16 v) {
  return __uint_as_float(((unsigned)v) << 16);
}

__device__ __forceinline__ float gelu_exact(float x) {
  return 0.5f * x * (1.0f + erff(x * 0.70710678118654752440f));
}

__device__ __forceinline__ float ln32(float x, float w, float b) {
  float m = x;
  m += __shfl_xor(m, 1); m += __shfl_xor(m, 2); m += __shfl_xor(m, 4);
  m += __shfl_xor(m, 8); m += __shfl_xor(m, 16);
  m *= (1.0f / 32.0f);
  float d = x - m;
  float v = d * d;
  v += __shfl_xor(v, 1); v += __shfl_xor(v, 2); v += __shfl_xor(v, 4);
  v += __shfl_xor(v, 8); v += __shfl_xor(v, 16);
  v *= (1.0f / 32.0f);
  return d * rsqrtf(v + EPSN) * w + b;
}

// ---------------- setup: CSR build, dst-range partitioned ----------------
__global__ void k_count_part(const int* __restrict__ dst, int* __restrict__ deg) {
  const int range = blockIdx.x & 7;
  const int sub = blockIdx.x >> 3;
  const int lo = range * RNG, hi = lo + RNG;
  for (int e = sub * 256 + threadIdx.x; e < N_EDGES; e += 256 * 256) {
    int d = dst[e];
    if (d >= lo && d < hi) atomicAdd(&deg[d], 1);
  }
}

__global__ void k_scatter_part(const int* __restrict__ src, const int* __restrict__ dst,
                               int* __restrict__ cur, int* __restrict__ ssrc) {
  const int range = blockIdx.x & 7;
  const int sub = blockIdx.x >> 3;
  const int lo = range * RNG, hi = lo + RNG;
  for (int e = sub * 256 + threadIdx.x; e < N_EDGES; e += 256 * 256) {
    int d = dst[e];
    if (d >= lo && d < hi) {
      int p = atomicAdd(&cur[d], 1);
      ssrc[p] = src[e];
    }
  }
}

__global__ void k_block_sums(const int* __restrict__ deg, int* __restrict__ bsum) {
  __shared__ int sh[256];
  int i = blockIdx.x * 256 + threadIdx.x;
  sh[threadIdx.x] = (i < N_NODES) ? deg[i] : 0;
  __syncthreads();
  for (int s = 128; s > 0; s >>= 1) {
    if (threadIdx.x < s) sh[threadIdx.x] += sh[threadIdx.x + s];
    __syncthreads();
  }
  if (threadIdx.x == 0) bsum[blockIdx.x] = sh[0];
}

__global__ void k_scan_bsums(int* __restrict__ bsum, int nb, int* __restrict__ off) {
  __shared__ int sh[512];
  int i = threadIdx.x;
  int v = (i < nb) ? bsum[i] : 0;
  sh[i] = v;
  __syncthreads();
  for (int s = 1; s < 512; s <<= 1) {
    int t = (i >= s) ? sh[i - s] : 0;
    __syncthreads();
    sh[i] += t;
    __syncthreads();
  }
  if (i < nb) bsum[i] = sh[i] - v;
  if (i == nb - 1) off[N_NODES] = sh[i];
}

__global__ void k_scan_final(const int* __restrict__ deg, const int* __restrict__ bsum,
                             int* __restrict__ off, int* __restrict__ cur) {
  __shared__ int sh[256];
  int i = blockIdx.x * 256 + threadIdx.x;
  int v = (i < N_NODES) ? deg[i] : 0;
  sh[threadIdx.x] = v;
  __syncthreads();
  for (int s = 1; s < 256; s <<= 1) {
    int t = (threadIdx.x >= s) ? sh[threadIdx.x - s] : 0;
    __syncthreads();
    sh[threadIdx.x] += t;
    __syncthreads();
  }
  if (i < N_NODES) {
    int ex = bsum[blockIdx.x] + sh[threadIdx.x] - v;
    off[i] = ex;
    cur[i] = ex;
  }
}

__global__ void k_graph_starts(const int* __restrict__ batch, int* __restrict__ gstart) {
  int g = threadIdx.x;
  if (g > N_GRAPHS) return;
  int lo = 0, hi = N_NODES;
  while (lo < hi) {
    int mid = (lo + hi) >> 1;
    if (batch[mid] < g) lo = mid + 1; else hi = mid;
  }
  gstart[g] = lo;
}

// ---------------- weight prep: fp32 -> bf16 B-fragment swizzle ----------------
#define W0S_ELEMS (4 * 9 * 64 * 8)
#define WGS_ELEMS (4 * 2 * 64 * 8)
__global__ void k_prep_w(const float* __restrict__ W0, const float* __restrict__ Wg,
                         u16* __restrict__ W0s, u16* __restrict__ Wgs) {
  int idx = blockIdx.x * 256 + threadIdx.x;
  if (idx < W0S_ELEMS) {
    int i = idx & 7, lane = (idx >> 3) & 63, ks = (idx >> 9) % 9, cb = idx / (9 * 512);
    int k = ks * 32 + (lane >> 4) * 8 + i, c = cb * 16 + (lane & 15);
    W0s[idx] = f2bf(k < IN_DIM ? W0[k * 64 + c] : 0.f);
  } else if (idx < W0S_ELEMS + GL * WGS_ELEMS) {
    int j = idx - W0S_ELEMS;
    int l = j / WGS_ELEMS, p = j % WGS_ELEMS;
    int i = p & 7, lane = (p >> 3) & 63, ks = (p >> 9) & 1, cb = p / (2 * 512);
    int k = ks * 32 + (lane >> 4) * 8 + i, c = cb * 16 + (lane & 15);
    Wgs[j] = f2bf(Wg[(size_t)l * 4096 + k * 64 + c]);
  }
}

// ---------------- per-layer: MFMA GEMM (T = X @ W, bf16) + attention logits ----------------
template <int KS, bool F32IN>
__global__ __launch_bounds__(256) void k_gemm_mfma(
    const void* __restrict__ Xin, const u16* __restrict__ Wswz,
    const float* __restrict__ a_src, const float* __restrict__ a_dst,
    u16* __restrict__ Tb, float* __restrict__ ES, float* __restrict__ ED) {
  const int lane = threadIdx.x & 63;
  const int wid = (blockIdx.x << 2) + (threadIdx.x >> 6);
  const int NT = N_NODES / 16;
  if (wid >= NT) return;
  const int grp = lane >> 4, n16 = lane & 15;
  float as_l[4], ad_l[4];
  #pragma unroll
  for (int cb = 0; cb < 4; ++cb) {
    as_l[cb] = a_src[cb * 16 + n16];
    ad_l[cb] = a_dst[cb * 16 + n16];
  }
  const long r0 = (long)wid * 16;

  bf16x8 afr[KS];
  if constexpr (!F32IN) {
    const u16* xrow = (const u16*)Xin + (r0 + n16) * (KS * 32) + grp * 8;
    #pragma unroll
    for (int ks = 0; ks < KS; ++ks) afr[ks] = *(const bf16x8*)(xrow + ks * 32);
  } else {
    const float* xr = (const float*)Xin + (r0 + n16) * (size_t)IN_DIM;
    #pragma unroll
    for (int ks = 0; ks < KS; ++ks) {
      bf16x8 a;
      #pragma unroll
      for (int i = 0; i < 8; ++i) {
        int k = ks * 32 + grp * 8 + i;
        float v = (k < IN_DIM) ? xr[k] : 0.f;
        a[i] = (short)f2bf(v);
      }
      afr[ks] = a;
    }
  }

  #pragma unroll
  for (int cb = 0; cb < 4; ++cb) {
    f32x4 a = {0.f, 0.f, 0.f, 0.f};
    #pragma unroll
    for (int ks = 0; ks < KS; ++ks) {
      bf16x8 b = *(const bf16x8*)(Wswz + ((size_t)(cb * KS + ks) * 64 + lane) * 8);
      a = __builtin_amdgcn_mfma_f32_16x16x32_bf16(afr[ks], b, a, 0, 0, 0);
    }
    #pragma unroll
    for (int r = 0; r < 4; ++r) {
      const long row = r0 + grp * 4 + r;
      float v = a[r];
      Tb[row * 64 + cb * 16 + n16] = f2bf(v);
      float s = v * as_l[cb];
      float d = v * ad_l[cb];
      s += __shfl_xor(s, 1); s += __shfl_xor(s, 2); s += __shfl_xor(s, 4); s += __shfl_xor(s, 8);
      d += __shfl_xor(d, 1); d += __shfl_xor(d, 2); d += __shfl_xor(d, 4); d += __shfl_xor(d, 8);
      if (n16 == 0) {
        ES[row * 4 + cb] = s;
        ED[row * 4 + cb] = d;
      }
    }
  }
}

// ---------------- per-layer: edge softmax + aggregate (round-7 form, bf16 F out) ----------------
__global__ __launch_bounds__(256) void k_edge_agg(
    const u16* __restrict__ Tb, const float* __restrict__ ES, const float* __restrict__ ED,
    const int* __restrict__ off, const int* __restrict__ ssrc,
    const float* __restrict__ bias, u16* __restrict__ Fb) {
  const int lane = threadIdx.x & 63;
  const int n = blockIdx.x * 4 + (threadIdx.x >> 6);
  if (n >= N_NODES) return;
  const int e0 = off[n];
  const int ec = off[n + 1] - e0;
  const int hd = lane & 3;
  const int qh = lane >> 4;
  const u16* Tl = Tb + lane;
  const float tself = bf2f(Tl[(long)n * 64]);   // issue early
  const float ed_h = ED[n * 4 + hd];
  float x0 = ES[n * 4 + hd] + ed_h;
  x0 = fmaxf(x0, 0.2f * x0);
  const float p0 = __expf(fminf(x0, 25.f));
  float s_run = p0;                              // per-lane head hd
  float acc = __shfl(p0, qh) * tself;            // my channel's head weight
  for (int base = 0; base < ec; base += 16) {
    const int eidx = base + (lane >> 2);
    const bool valid = eidx < ec;
    const int sv = valid ? ssrc[e0 + eidx] : n;
    // T-row gathers first: overlap with ES gather below
    int rows[16];
    #pragma unroll
    for (int e = 0; e < 16; ++e) rows[e] = __shfl(sv, e << 2);
    float tv[16];
    #pragma unroll
    for (int e = 0; e < 16; ++e) tv[e] = bf2f(Tl[(long)rows[e] * 64]);
    // logits
    float v = ES[sv * 4 + hd] + ed_h;
    v = fmaxf(v, 0.2f * v);
    const float p = valid ? __expf(fminf(v, 25.f)) : 0.f;
    float ps = p;
    ps += __shfl_xor(ps, 4); ps += __shfl_xor(ps, 8);
    ps += __shfl_xor(ps, 16); ps += __shfl_xor(ps, 32);
    s_run += ps;
    #pragma unroll
    for (int e = 0; e < 16; ++e)
      acc = fmaf(__shfl(p, (e << 2) | qh), tv[e], acc);
  }
  const float s_q = __shfl(s_run, qh);
  const float o = acc / (s_q + 1e-16f) + bias[lane];
  Fb[(long)n * 64 + lane] = f2bf(gelu_exact(o));
}

// ---------------- GraphNorm: moments + stats fused (last-block pattern) ----------------
template <bool BF16IN>
__global__ void k_moments_stats(const void* __restrict__ Fv, const int* __restrict__ gstart,
                                const float* __restrict__ ms,
                                float* __restrict__ SP, float* __restrict__ SQP,
                                float* __restrict__ MM, float* __restrict__ IS,
                                int* __restrict__ cnt, int compute_stats) {
  const int g = blockIdx.x;
  const int s0 = gstart[g];
  const int rows = gstart[g + 1] - s0;
  const int lane = threadIdx.x & 63;
  const int w = threadIdx.x >> 6;
  float sum = 0.f, sq = 0.f;
  for (int r = blockIdx.y * 4 + w; r < rows; r += gridDim.y * 4) {
    float v;
    if constexpr (BF16IN) v = bf2f(((const u16*)Fv)[(long)(s0 + r) * 64 + lane]);
    else v = ((const float*)Fv)[(long)(s0 + r) * 64 + lane];
    sum += v;
    sq = fmaf(v, v, sq);
  }
  __shared__ float ls[4][64];
  __shared__ float lq[4][64];
  __shared__ int lastdone;
  ls[w][lane] = sum;
  lq[w][lane] = sq;
  __syncthreads();
  if (threadIdx.x < 64) {
    float a = ls[0][lane] + ls[1][lane] + ls[2][lane] + ls[3][lane];
    float b = lq[0][lane] + lq[1][lane] + lq[2][lane] + lq[3][lane];
    SP[(blockIdx.y * N_GRAPHS + g) * 64 + lane] = a;
    SQP[(blockIdx.y * N_GRAPHS + g) * 64 + lane] = b;
    __threadfence();
  }
  __syncthreads();
  if (threadIdx.x == 0) {
    lastdone = 0;
    if (compute_stats) {
      int c = atomicAdd(cnt, 1);
      lastdone = (c == N_GRAPHS * NPART - 1) ? 1 : 0;
    }
  }
  __syncthreads();
  if (lastdone) {
    __threadfence();
    for (int i = threadIdx.x; i < N_GRAPHS * 64; i += blockDim.x) {
      int gg = i >> 6, c = i & 63;
      float s = 0.f, q = 0.f;
      #pragma unroll
      for (int b2 = 0; b2 < NPART; ++b2) {
        s += SP[(b2 * N_GRAPHS + gg) * 64 + c];
        q += SQP[(b2 * N_GRAPHS + gg) * 64 + c];
      }
      float cntf = fmaxf((float)(gstart[gg + 1] - gstart[gg]), 1.0f);
      float mean = s / cntf;
      float mm = mean * ms[c];
      float var = q / cntf - 2.f * mm * mean + mm * mm;
      MM[i] = mm;
      IS[i] = rsqrtf(fmaxf(var, 0.f) + EPSN);
    }
    if (threadIdx.x == 0) *cnt = 0;
  }
}

__global__ void k_norm_res(const u16* __restrict__ Fb, const int* __restrict__ batch,
                           const float* __restrict__ MM, const float* __restrict__ IS,
                           const float* __restrict__ w, const float* __restrict__ b,
                           float* __restrict__ X, u16* __restrict__ Xb, int residual) {
  const long i4 = (long)blockIdx.x * 256 + threadIdx.x;
  const int n = (int)(i4 >> 4);
  const int c4 = (int)(i4 & 15) << 2;
  const int g = batch[n];
  ushort4 fu = *(const ushort4*)(Fb + i4 * 4);
  float4 f = make_float4(bf2f(fu.x), bf2f(fu.y), bf2f(fu.z), bf2f(fu.w));
  float4 mm = *(const float4*)(MM + g * 64 + c4);
  float4 is = *(const float4*)(IS + g * 64 + c4);
  float4 wv = *(const float4*)(w + c4);
  float4 bv = *(const float4*)(b + c4);
  float4 y;
  y.x = fmaf(wv.x * (f.x - mm.x), is.x, bv.x);
  y.y = fmaf(wv.y * (f.y - mm.y), is.y, bv.y);
  y.z = fmaf(wv.z * (f.z - mm.z), is.z, bv.z);
  y.w = fmaf(wv.w * (f.w - mm.w), is.w, bv.w);
  float4* xp = (float4*)(X + i4 * 4);
  if (residual) {
    float4 xo = *xp;
    y.x += xo.x; y.y += xo.y; y.z += xo.z; y.w += xo.w;
  }
  *xp = y;
  union { u16 s[4]; unsigned long long ll; } pk;
  pk.s[0] = f2bf(y.x); pk.s[1] = f2bf(y.y); pk.s[2] = f2bf(y.z); pk.s[3] = f2bf(y.w);
  *(unsigned long long*)(Xb + i4 * 4) = pk.ll;
}

// ---------------- pooled MLP head (one block) ----------------
__global__ __launch_bounds__(512) void k_mlp(
    const float* __restrict__ SP, const int* __restrict__ gstart, const float* __restrict__ gf,
    const float* __restrict__ W0, const float* __restrict__ b0,
    const float* __restrict__ lw0, const float* __restrict__ lb0,
    const float* __restrict__ Wg, const float* __restrict__ bg,
    const float* __restrict__ lwg, const float* __restrict__ lbg,
    const float* __restrict__ hW, const float* __restrict__ hb,
    float* __restrict__ out) {
  __shared__ float P[16][88];
  __shared__ float Z[16][32];
  const int tid = threadIdx.x;
  for (int i = tid; i < 16 * 88; i += 512) {
    int g = i / 88, c = i - g * 88;
    float v;
    if (c < 64) {
      float s = 0.f;
      #pragma unroll
      for (int b = 0; b < NPART; ++b) s += SP[(b * N_GRAPHS + g) * 64 + c];
      float cnt = fmaxf((float)(gstart[g + 1] - gstart[g]), 1.0f);
      v = s / cnt;
    } else {
      v = gf[g * GDIM + (c - 64)];
    }
    P[g][c] = v;
  }
  __syncthreads();
  const int g = tid >> 5, c = tid & 31;
  float acc = b0[c];
  for (int k = 0; k < 88; ++k) acc = fmaf(P[g][k], W0[k * 32 + c], acc);
  float z = ln32(gelu_exact(acc), lw0[c], lb0[c]);
  for (int l = 0; l < LL; ++l) {
    Z[g][c] = z;
    __syncthreads();
    float a2 = bg[l * 32 + c];
    const float* Wl = Wg + l * 32 * 32;
    for (int k = 0; k < 32; ++k) a2 = fmaf(Z[g][k], Wl[k * 32 + c], a2);
    __syncthreads();
    z = ln32(gelu_exact(a2), lwg[l * 32 + c], lbg[l * 32 + c]) + z;
  }
  Z[g][c] = z * hW[c];
  __syncthreads();
  if (c == 0) {
    float s = 0.f;
    for (int k = 0; k < 32; ++k) s += Z[g][k];
    out[g] = s + hb[0];
  }
}

extern "C" void kernel_launch(void* const* d_in, const int* in_sizes, int n_in,
                              void* d_out, int out_size, void* d_ws, size_t ws_size,
                              hipStream_t stream) {
  const float* x   = (const float*)d_in[0];
  const int*   ei  = (const int*)d_in[1];
  const int* batch = (const int*)d_in[2];
  const float* gf  = (const float*)d_in[3];
  const float* W0  = (const float*)d_in[4];
  const float* as0 = (const float*)d_in[5];
  const float* ad0 = (const float*)d_in[6];
  const float* b0  = (const float*)d_in[7];
  const float* gw0 = (const float*)d_in[8];
  const float* gb0 = (const float*)d_in[9];
  const float* gm0 = (const float*)d_in[10];
  const float* Wg  = (const float*)d_in[11];
  const float* asg = (const float*)d_in[12];
  const float* adg = (const float*)d_in[13];
  const float* bg  = (const float*)d_in[14];
  const float* gwg = (const float*)d_in[15];
  const float* gbg = (const float*)d_in[16];
  const float* gmg = (const float*)d_in[17];
  const float* mW0 = (const float*)d_in[18];
  const float* mb0 = (const float*)d_in[19];
  const float* lw0 = (const float*)d_in[20];
  const float* lb0 = (const float*)d_in[21];
  const float* mWg = (const float*)d_in[22];
  const float* mbg = (const float*)d_in[23];
  const float* lwg = (const float*)d_in[24];
  const float* lbg = (const float*)d_in[25];
  const float* hW  = (const float*)d_in[26];
  const float* hb  = (const float*)d_in[27];
  float* out = (float*)d_out;
  const int* src = ei;
  const int* dst = ei + N_EDGES;

  char* p = (char*)d_ws;
  auto alloc = [&](size_t bytes) {
    char* r = p;
    p += (bytes + 255) & ~(size_t)255;
    return (void*)r;
  };
  float* X   = (float*)alloc((size_t)N_NODES * 64 * 4);
  u16*   Fb  = (u16*)alloc((size_t)N_NODES * 64 * 2);
  u16*   Xb  = (u16*)alloc((size_t)N_NODES * 64 * 2);
  u16*   Tb  = (u16*)alloc((size_t)N_NODES * 64 * 2);
  float* ES  = (float*)alloc((size_t)N_NODES * 4 * 4);
  float* ED  = (float*)alloc((size_t)N_NODES * 4 * 4);
  int* ssrc  = (int*)alloc((size_t)N_EDGES * 4);
  int* deg   = (int*)alloc((size_t)N_NODES * 4);
  int* off   = (int*)alloc((size_t)(N_NODES + 1) * 4);
  int* cur   = (int*)alloc((size_t)N_NODES * 4);
  int* bsum  = (int*)alloc(4096);
  int* gstart = (int*)alloc((N_GRAPHS + 1) * 4);
  u16* W0s   = (u16*)alloc((size_t)W0S_ELEMS * 2);
  u16* Wgs   = (u16*)alloc((size_t)GL * WGS_ELEMS * 2);
  float* SP  = (float*)alloc(NPART * N_GRAPHS * 64 * 4);
  float* SQP = (float*)alloc(NPART * N_GRAPHS * 64 * 4);
  float* MM  = (float*)alloc(N_GRAPHS * 64 * 4);
  float* IS  = (float*)alloc(N_GRAPHS * 64 * 4);
  int* cnt   = (int*)alloc(256);
  (void)ws_size; (void)in_sizes; (void)n_in; (void)out_size;

  const int NB = (N_NODES + 255) / 256;
  hipMemsetAsync(deg, 0, (size_t)N_NODES * 4, stream);
  hipMemsetAsync(cnt, 0, 256, stream);
  k_count_part<<<2048, 256, 0, stream>>>(dst, deg);
  k_block_sums<<<NB, 256, 0, stream>>>(deg, bsum);
  k_scan_bsums<<<1, 512, 0, stream>>>(bsum, NB, off);
  k_scan_final<<<NB, 256, 0, stream>>>(deg, bsum, off, cur);
  k_scatter_part<<<2048, 256, 0, stream>>>(src, dst, cur, ssrc);
  k_graph_starts<<<1, 32, 0, stream>>>(batch, gstart);
  k_prep_w<<<(W0S_ELEMS + GL * WGS_ELEMS + 255) / 256, 256, 0, stream>>>(W0, Wg, W0s, Wgs);

  const int GG = (N_NODES / 16 + 3) / 4;
  for (int l = 0; l < 1 + GL; ++l) {
    const float* asl = (l == 0) ? as0 : (asg + (size_t)(l - 1) * 64);
    const float* adl = (l == 0) ? ad0 : (adg + (size_t)(l - 1) * 64);
    const float* bl  = (l == 0) ? b0  : (bg  + (size_t)(l - 1) * 64);
    const float* gwl = (l == 0) ? gw0 : (gwg + (size_t)(l - 1) * 64);
    const float* gbl = (l == 0) ? gb0 : (gbg + (size_t)(l - 1) * 64);
    const float* gml = (l == 0) ? gm0 : (gmg + (size_t)(l - 1) * 64);
    if (l == 0)
      k_gemm_mfma<9, true><<<GG, 256, 0, stream>>>(x, W0s, asl, adl, Tb, ES, ED);
    else
      k_gemm_mfma<2, false><<<GG, 256, 0, stream>>>(Xb, Wgs + (size_t)(l - 1) * WGS_ELEMS,
                                                    asl, adl, Tb, ES, ED);
    k_edge_agg<<<N_NODES / 4, 256, 0, stream>>>(Tb, ES, ED, off, ssrc, bl, Fb);
    k_moments_stats<true><<<dim3(N_GRAPHS, NPART), 256, 0, stream>>>(Fb, gstart, gml, SP, SQP, MM, IS, cnt, 1);
    k_norm_res<<<(N_NODES * 64) / 1024, 256, 0, stream>>>(Fb, batch, MM, IS, gwl, gbl, X, Xb, l > 0);
  }

  k_moments_stats<false><<<dim3(N_GRAPHS, NPART), 256, 0, stream>>>(X, gstart, gm0, SP, SQP, MM, IS, cnt, 0);
  k_mlp<<<1, 512, 0, stream>>>(SP, gstart, gf, mW0, mb0, lw0, lb0,
                               mWg, mbg, lwg, lbg, hW, hb, out);
}

// Round 10
// 892.740 us; speedup vs baseline: 1.5441x; 1.1076x over previous
//
#include <hip/hip_runtime.h>
#include <math.h>

#define N_NODES 100000
#define N_EDGES 1200000
#define N_GRAPHS 16
#define CH 64
#define HEADS 4
#define GL 6
#define IN_DIM 261
#define GDIM 24
#define LIN 32
#define LL 3
#define EPSN 1e-5f
#define NPART 16           // final-pool moments partials
#define MPART 64           // per-layer moment partial copies (edge_agg atomics)
#define RNG (N_NODES / 8)  // 12500 nodes per dst-range

typedef unsigned short u16;
typedef __attribute__((ext_vector_type(8))) short bf16x8;
typedef __attribute__((ext_vector_type(4))) float f32x4;

__device__ __forceinline__ u16 f2bf(float f) {
  unsigned u = __float_as_uint(f);
  u = (u + 0x7FFFu + ((u >> 16) & 1u)) >> 16;
  return (u16)u;
}
__device__ __forceinline__ float bf2f(u16 v) {
  return __uint_as_float(((unsigned)v) << 16);
}

__device__ __forceinline__ float gelu_exact(float x) {
  return 0.5f * x * (1.0f + erff(x * 0.70710678118654752440f));
}

__device__ __forceinline__ float ln32(float x, float w, float b) {
  float m = x;
  m += __shfl_xor(m, 1); m += __shfl_xor(m, 2); m += __shfl_xor(m, 4);
  m += __shfl_xor(m, 8); m += __shfl_xor(m, 16);
  m *= (1.0f / 32.0f);
  float d = x - m;
  float v = d * d;
  v += __shfl_xor(v, 1); v += __shfl_xor(v, 2); v += __shfl_xor(v, 4);
  v += __shfl_xor(v, 8); v += __shfl_xor(v, 16);
  v *= (1.0f / 32.0f);
  return d * rsqrtf(v + EPSN) * w + b;
}

// ---------------- setup: CSR build, dst-range partitioned ----------------
__global__ void k_count_part(const int* __restrict__ dst, int* __restrict__ deg) {
  const int range = blockIdx.x & 7;
  const int sub = blockIdx.x >> 3;
  const int lo = range * RNG, hi = lo + RNG;
  for (int e = sub * 256 + threadIdx.x; e < N_EDGES; e += 256 * 256) {
    int d = dst[e];
    if (d >= lo && d < hi) atomicAdd(&deg[d], 1);
  }
}

__global__ void k_scatter_part(const int* __restrict__ src, const int* __restrict__ dst,
                               int* __restrict__ cur, int* __restrict__ ssrc) {
  const int range = blockIdx.x & 7;
  const int sub = blockIdx.x >> 3;
  const int lo = range * RNG, hi = lo + RNG;
  for (int e = sub * 256 + threadIdx.x; e < N_EDGES; e += 256 * 256) {
    int d = dst[e];
    if (d >= lo && d < hi) {
      int p = atomicAdd(&cur[d], 1);
      ssrc[p] = src[e];
    }
  }
}

__global__ void k_block_sums(const int* __restrict__ deg, int* __restrict__ bsum) {
  __shared__ int sh[256];
  int i = blockIdx.x * 256 + threadIdx.x;
  sh[threadIdx.x] = (i < N_NODES) ? deg[i] : 0;
  __syncthreads();
  for (int s = 128; s > 0; s >>= 1) {
    if (threadIdx.x < s) sh[threadIdx.x] += sh[threadIdx.x + s];
    __syncthreads();
  }
  if (threadIdx.x == 0) bsum[blockIdx.x] = sh[0];
}

__global__ void k_scan_bsums(int* __restrict__ bsum, int nb, int* __restrict__ off) {
  __shared__ int sh[512];
  int i = threadIdx.x;
  int v = (i < nb) ? bsum[i] : 0;
  sh[i] = v;
  __syncthreads();
  for (int s = 1; s < 512; s <<= 1) {
    int t = (i >= s) ? sh[i - s] : 0;
    __syncthreads();
    sh[i] += t;
    __syncthreads();
  }
  if (i < nb) bsum[i] = sh[i] - v;
  if (i == nb - 1) off[N_NODES] = sh[i];
}

__global__ void k_scan_final(const int* __restrict__ deg, const int* __restrict__ bsum,
                             int* __restrict__ off, int* __restrict__ cur) {
  __shared__ int sh[256];
  int i = blockIdx.x * 256 + threadIdx.x;
  int v = (i < N_NODES) ? deg[i] : 0;
  sh[threadIdx.x] = v;
  __syncthreads();
  for (int s = 1; s < 256; s <<= 1) {
    int t = (threadIdx.x >= s) ? sh[threadIdx.x - s] : 0;
    __syncthreads();
    sh[threadIdx.x] += t;
    __syncthreads();
  }
  if (i < N_NODES) {
    int ex = bsum[blockIdx.x] + sh[threadIdx.x] - v;
    off[i] = ex;
    cur[i] = ex;
  }
}

__global__ void k_graph_starts(const int* __restrict__ batch, int* __restrict__ gstart) {
  int g = threadIdx.x;
  if (g > N_GRAPHS) return;
  int lo = 0, hi = N_NODES;
  while (lo < hi) {
    int mid = (lo + hi) >> 1;
    if (batch[mid] < g) lo = mid + 1; else hi = mid;
  }
  gstart[g] = lo;
}

// ---------------- weight prep: fp32 -> bf16 B-fragment swizzle ----------------
#define W0S_ELEMS (4 * 9 * 64 * 8)
#define WGS_ELEMS (4 * 2 * 64 * 8)
__global__ void k_prep_w(const float* __restrict__ W0, const float* __restrict__ Wg,
                         u16* __restrict__ W0s, u16* __restrict__ Wgs) {
  int idx = blockIdx.x * 256 + threadIdx.x;
  if (idx < W0S_ELEMS) {
    int i = idx & 7, lane = (idx >> 3) & 63, ks = (idx >> 9) % 9, cb = idx / (9 * 512);
    int k = ks * 32 + (lane >> 4) * 8 + i, c = cb * 16 + (lane & 15);
    W0s[idx] = f2bf(k < IN_DIM ? W0[k * 64 + c] : 0.f);
  } else if (idx < W0S_ELEMS + GL * WGS_ELEMS) {
    int j = idx - W0S_ELEMS;
    int l = j / WGS_ELEMS, p = j % WGS_ELEMS;
    int i = p & 7, lane = (p >> 3) & 63, ks = (p >> 9) & 1, cb = p / (2 * 512);
    int k = ks * 32 + (lane >> 4) * 8 + i, c = cb * 16 + (lane & 15);
    Wgs[j] = f2bf(Wg[(size_t)l * 4096 + k * 64 + c]);
  }
}

// ---------------- layer 0: standalone MFMA GEMM + logits ----------------
__global__ __launch_bounds__(256) void k_gemm0(
    const float* __restrict__ Xin, const u16* __restrict__ Wswz,
    const float* __restrict__ a_src, const float* __restrict__ a_dst,
    u16* __restrict__ Tb, float* __restrict__ ES, float* __restrict__ ED) {
  const int lane = threadIdx.x & 63;
  const int wid = (blockIdx.x << 2) + (threadIdx.x >> 6);
  const int NT = N_NODES / 16;
  if (wid >= NT) return;
  const int grp = lane >> 4, n16 = lane & 15;
  float as_l[4], ad_l[4];
  #pragma unroll
  for (int cb = 0; cb < 4; ++cb) {
    as_l[cb] = a_src[cb * 16 + n16];
    ad_l[cb] = a_dst[cb * 16 + n16];
  }
  const long r0 = (long)wid * 16;

  bf16x8 afr[9];
  const float* xr = Xin + (r0 + n16) * (size_t)IN_DIM;
  #pragma unroll
  for (int ks = 0; ks < 9; ++ks) {
    bf16x8 a;
    #pragma unroll
    for (int i = 0; i < 8; ++i) {
      int k = ks * 32 + grp * 8 + i;
      float v = (k < IN_DIM) ? xr[k] : 0.f;
      a[i] = (short)f2bf(v);
    }
    afr[ks] = a;
  }

  #pragma unroll
  for (int cb = 0; cb < 4; ++cb) {
    f32x4 a = {0.f, 0.f, 0.f, 0.f};
    #pragma unroll
    for (int ks = 0; ks < 9; ++ks) {
      bf16x8 b = *(const bf16x8*)(Wswz + ((size_t)(cb * 9 + ks) * 64 + lane) * 8);
      a = __builtin_amdgcn_mfma_f32_16x16x32_bf16(afr[ks], b, a, 0, 0, 0);
    }
    #pragma unroll
    for (int r = 0; r < 4; ++r) {
      const long row = r0 + grp * 4 + r;
      float v = a[r];
      Tb[row * 64 + cb * 16 + n16] = f2bf(v);
      float s = v * as_l[cb];
      float d = v * ad_l[cb];
      s += __shfl_xor(s, 1); s += __shfl_xor(s, 2); s += __shfl_xor(s, 4); s += __shfl_xor(s, 8);
      d += __shfl_xor(d, 1); d += __shfl_xor(d, 2); d += __shfl_xor(d, 4); d += __shfl_xor(d, 8);
      if (n16 == 0) {
        ES[row * 4 + cb] = s;
        ED[row * 4 + cb] = d;
      }
    }
  }
}

// ---------------- edge softmax + aggregate + moment partials ----------------
__global__ __launch_bounds__(256) void k_edge_agg(
    const u16* __restrict__ Tb, const float* __restrict__ ES, const float* __restrict__ ED,
    const int* __restrict__ off, const int* __restrict__ ssrc,
    const float* __restrict__ bias, const int* __restrict__ batch,
    u16* __restrict__ Fb, float* __restrict__ SPp, float* __restrict__ SQp) {
  const int lane = threadIdx.x & 63;
  const int n = blockIdx.x * 4 + (threadIdx.x >> 6);
  if (n >= N_NODES) return;
  const int e0 = off[n];
  const int ec = off[n + 1] - e0;
  const int hd = lane & 3;
  const int qh = lane >> 4;
  const u16* Tl = Tb + lane;
  const float tself = bf2f(Tl[(long)n * 64]);   // issue early
  const float ed_h = ED[n * 4 + hd];
  float x0 = ES[n * 4 + hd] + ed_h;
  x0 = fmaxf(x0, 0.2f * x0);
  const float p0 = __expf(fminf(x0, 25.f));
  float s_run = p0;
  float acc = __shfl(p0, qh) * tself;
  for (int base = 0; base < ec; base += 16) {
    const int eidx = base + (lane >> 2);
    const bool valid = eidx < ec;
    const int sv = valid ? ssrc[e0 + eidx] : n;
    int rows[16];
    #pragma unroll
    for (int e = 0; e < 16; ++e) rows[e] = __shfl(sv, e << 2);
    float tv[16];
    #pragma unroll
    for (int e = 0; e < 16; ++e) tv[e] = bf2f(Tl[(long)rows[e] * 64]);
    float v = ES[sv * 4 + hd] + ed_h;
    v = fmaxf(v, 0.2f * v);
    const float p = valid ? __expf(fminf(v, 25.f)) : 0.f;
    float ps = p;
    ps += __shfl_xor(ps, 4); ps += __shfl_xor(ps, 8);
    ps += __shfl_xor(ps, 16); ps += __shfl_xor(ps, 32);
    s_run += ps;
    #pragma unroll
    for (int e = 0; e < 16; ++e)
      acc = fmaf(__shfl(p, (e << 2) | qh), tv[e], acc);
  }
  const float s_q = __shfl(s_run, qh);
  const float o = acc / (s_q + 1e-16f) + bias[lane];
  const float f = gelu_exact(o);
  Fb[(long)n * 64 + lane] = f2bf(f);
  // moment partials (64 copies; ~100 collisions/address)
  const int part = blockIdx.x & (MPART - 1);
  const int g = batch[n];
  atomicAdd(&SPp[((size_t)part * N_GRAPHS + g) * 64 + lane], f);
  atomicAdd(&SQp[((size_t)part * N_GRAPHS + g) * 64 + lane], f * f);
}

// ---------------- per-layer stats: reduce partials -> MM/IS, re-zero ----------------
__global__ void k_stats(const int* __restrict__ gstart, const float* __restrict__ ms,
                        float* __restrict__ SPp, float* __restrict__ SQp,
                        float* __restrict__ MM, float* __restrict__ IS) {
  const int g = blockIdx.x;
  const int t = threadIdx.x;         // 256
  const int c = t & 63, chunk = t >> 6;
  float s = 0.f, q = 0.f;
  for (int p2 = chunk * 16; p2 < chunk * 16 + 16; ++p2) {
    s += SPp[((size_t)p2 * N_GRAPHS + g) * 64 + c];
    q += SQp[((size_t)p2 * N_GRAPHS + g) * 64 + c];
  }
  __shared__ float ls[4][64];
  __shared__ float lq[4][64];
  ls[chunk][c] = s;
  lq[chunk][c] = q;
  __syncthreads();
  if (t < 64) {
    s = ls[0][t] + ls[1][t] + ls[2][t] + ls[3][t];
    q = lq[0][t] + lq[1][t] + lq[2][t] + lq[3][t];
    float cnt = fmaxf((float)(gstart[g + 1] - gstart[g]), 1.0f);
    float mean = s / cnt;
    float mm = mean * ms[t];
    float var = q / cnt - 2.f * mm * mean + mm * mm;
    MM[g * 64 + t] = mm;
    IS[g * 64 + t] = rsqrtf(fmaxf(var, 0.f) + EPSN);
  }
  __syncthreads();
  for (int p2 = chunk * 16; p2 < chunk * 16 + 16; ++p2) {
    SPp[((size_t)p2 * N_GRAPHS + g) * 64 + c] = 0.f;
    SQp[((size_t)p2 * N_GRAPHS + g) * 64 + c] = 0.f;
  }
}

// ---------------- fused: GraphNorm + residual + NEXT layer's GEMM + logits ----------------
// One block = 16 nodes = one MFMA tile. 4 waves, wave wid owns col-block cb=wid.
__global__ __launch_bounds__(256) void k_norm_gemm(
    const u16* __restrict__ Fb, const int* __restrict__ batch,
    const float* __restrict__ MM, const float* __restrict__ IS,
    const float* __restrict__ w, const float* __restrict__ b,
    const u16* __restrict__ Wswz, const float* __restrict__ a_src,
    const float* __restrict__ a_dst, float* __restrict__ X, int residual,
    u16* __restrict__ Tb, float* __restrict__ ES, float* __restrict__ ED) {
  __shared__ __align__(16) u16 sY[16][72];   // 144B rows: 16B-aligned
  const int tid = threadIdx.x;
  const long n0 = (long)blockIdx.x * 16;
  // --- norm + residual (thread = node tid>>4, channels c4..c4+3) ---
  {
    const int node = tid >> 4;
    const int c4 = (tid & 15) << 2;
    const long n = n0 + node;
    const int g = batch[n];
    ushort4 fu = *(const ushort4*)(Fb + n * 64 + c4);
    float4 f = make_float4(bf2f(fu.x), bf2f(fu.y), bf2f(fu.z), bf2f(fu.w));
    float4 mm = *(const float4*)(MM + g * 64 + c4);
    float4 is = *(const float4*)(IS + g * 64 + c4);
    float4 wv = *(const float4*)(w + c4);
    float4 bv = *(const float4*)(b + c4);
    float4 y;
    y.x = fmaf(wv.x * (f.x - mm.x), is.x, bv.x);
    y.y = fmaf(wv.y * (f.y - mm.y), is.y, bv.y);
    y.z = fmaf(wv.z * (f.z - mm.z), is.z, bv.z);
    y.w = fmaf(wv.w * (f.w - mm.w), is.w, bv.w);
    float4* xp = (float4*)(X + n * 64 + c4);
    if (residual) {
      float4 xo = *xp;
      y.x += xo.x; y.y += xo.y; y.z += xo.z; y.w += xo.w;
    }
    *xp = y;
    union { u16 s[4]; unsigned long long ll; } pk;
    pk.s[0] = f2bf(y.x); pk.s[1] = f2bf(y.y); pk.s[2] = f2bf(y.z); pk.s[3] = f2bf(y.w);
    *(unsigned long long*)&sY[node][c4] = pk.ll;
  }
  __syncthreads();
  // --- gemm: wave wid computes col-block cb=wid for the block's 16 rows ---
  const int lane = tid & 63;
  const int wid = tid >> 6;
  const int grp = lane >> 4, n16 = lane & 15;
  bf16x8 afr[2];
  #pragma unroll
  for (int ks = 0; ks < 2; ++ks)
    afr[ks] = *(const bf16x8*)(&sY[n16][ks * 32 + grp * 8]);
  f32x4 a = {0.f, 0.f, 0.f, 0.f};
  #pragma unroll
  for (int ks = 0; ks < 2; ++ks) {
    bf16x8 bb = *(const bf16x8*)(Wswz + ((size_t)(wid * 2 + ks) * 64 + lane) * 8);
    a = __builtin_amdgcn_mfma_f32_16x16x32_bf16(afr[ks], bb, a, 0, 0, 0);
  }
  const float as_c = a_src[wid * 16 + n16];
  const float ad_c = a_dst[wid * 16 + n16];
  #pragma unroll
  for (int r = 0; r < 4; ++r) {
    const long row = n0 + grp * 4 + r;
    float v = a[r];
    Tb[row * 64 + wid * 16 + n16] = f2bf(v);
    float s = v * as_c;
    float d = v * ad_c;
    s += __shfl_xor(s, 1); s += __shfl_xor(s, 2); s += __shfl_xor(s, 4); s += __shfl_xor(s, 8);
    d += __shfl_xor(d, 1); d += __shfl_xor(d, 2); d += __shfl_xor(d, 4); d += __shfl_xor(d, 8);
    if (n16 == 0) {
      ES[row * 4 + wid] = s;
      ED[row * 4 + wid] = d;
    }
  }
}

// ---------------- last layer: plain norm + residual ----------------
__global__ void k_norm_res(const u16* __restrict__ Fb, const int* __restrict__ batch,
                           const float* __restrict__ MM, const float* __restrict__ IS,
                           const float* __restrict__ w, const float* __restrict__ b,
                           float* __restrict__ X) {
  const long i4 = (long)blockIdx.x * 256 + threadIdx.x;
  const int n = (int)(i4 >> 4);
  const int c4 = (int)(i4 & 15) << 2;
  const int g = batch[n];
  ushort4 fu = *(const ushort4*)(Fb + i4 * 4);
  float4 f = make_float4(bf2f(fu.x), bf2f(fu.y), bf2f(fu.z), bf2f(fu.w));
  float4 mm = *(const float4*)(MM + g * 64 + c4);
  float4 is = *(const float4*)(IS + g * 64 + c4);
  float4 wv = *(const float4*)(w + c4);
  float4 bv = *(const float4*)(b + c4);
  float4 y;
  y.x = fmaf(wv.x * (f.x - mm.x), is.x, bv.x);
  y.y = fmaf(wv.y * (f.y - mm.y), is.y, bv.y);
  y.z = fmaf(wv.z * (f.z - mm.z), is.z, bv.z);
  y.w = fmaf(wv.w * (f.w - mm.w), is.w, bv.w);
  float4* xp = (float4*)(X + i4 * 4);
  float4 xo = *xp;
  y.x += xo.x; y.y += xo.y; y.z += xo.z; y.w += xo.w;
  *xp = y;
}

// ---------------- final pooling moments (fp32 X, 16 partials) ----------------
__global__ void k_moments_final(const float* __restrict__ X, const int* __restrict__ gstart,
                                float* __restrict__ SP, float* __restrict__ SQP) {
  const int g = blockIdx.x;
  const int s0 = gstart[g];
  const int rows = gstart[g + 1] - s0;
  const int lane = threadIdx.x & 63;
  const int w = threadIdx.x >> 6;
  float sum = 0.f;
  for (int r = blockIdx.y * 4 + w; r < rows; r += gridDim.y * 4)
    sum += X[(long)(s0 + r) * 64 + lane];
  __shared__ float ls[4][64];
  ls[w][lane] = sum;
  __syncthreads();
  if (threadIdx.x < 64) {
    float a = ls[0][lane] + ls[1][lane] + ls[2][lane] + ls[3][lane];
    SP[(blockIdx.y * N_GRAPHS + g) * 64 + lane] = a;
  }
  (void)SQP;
}

// ---------------- pooled MLP head (one block) ----------------
__global__ __launch_bounds__(512) void k_mlp(
    const float* __restrict__ SP, const int* __restrict__ gstart, const float* __restrict__ gf,
    const float* __restrict__ W0, const float* __restrict__ b0,
    const float* __restrict__ lw0, const float* __restrict__ lb0,
    const float* __restrict__ Wg, const float* __restrict__ bg,
    const float* __restrict__ lwg, const float* __restrict__ lbg,
    const float* __restrict__ hW, const float* __restrict__ hb,
    float* __restrict__ out) {
  __shared__ float P[16][88];
  __shared__ float Z[16][32];
  const int tid = threadIdx.x;
  for (int i = tid; i < 16 * 88; i += 512) {
    int g = i / 88, c = i - g * 88;
    float v;
    if (c < 64) {
      float s = 0.f;
      #pragma unroll
      for (int b = 0; b < NPART; ++b) s += SP[(b * N_GRAPHS + g) * 64 + c];
      float cnt = fmaxf((float)(gstart[g + 1] - gstart[g]), 1.0f);
      v = s / cnt;
    } else {
      v = gf[g * GDIM + (c - 64)];
    }
    P[g][c] = v;
  }
  __syncthreads();
  const int g = tid >> 5, c = tid & 31;
  float acc = b0[c];
  for (int k = 0; k < 88; ++k) acc = fmaf(P[g][k], W0[k * 32 + c], acc);
  float z = ln32(gelu_exact(acc), lw0[c], lb0[c]);
  for (int l = 0; l < LL; ++l) {
    Z[g][c] = z;
    __syncthreads();
    float a2 = bg[l * 32 + c];
    const float* Wl = Wg + l * 32 * 32;
    for (int k = 0; k < 32; ++k) a2 = fmaf(Z[g][k], Wl[k * 32 + c], a2);
    __syncthreads();
    z = ln32(gelu_exact(a2), lwg[l * 32 + c], lbg[l * 32 + c]) + z;
  }
  Z[g][c] = z * hW[c];
  __syncthreads();
  if (c == 0) {
    float s = 0.f;
    for (int k = 0; k < 32; ++k) s += Z[g][k];
    out[g] = s + hb[0];
  }
}

extern "C" void kernel_launch(void* const* d_in, const int* in_sizes, int n_in,
                              void* d_out, int out_size, void* d_ws, size_t ws_size,
                              hipStream_t stream) {
  const float* x   = (const float*)d_in[0];
  const int*   ei  = (const int*)d_in[1];
  const int* batch = (const int*)d_in[2];
  const float* gf  = (const float*)d_in[3];
  const float* W0  = (const float*)d_in[4];
  const float* as0 = (const float*)d_in[5];
  const float* ad0 = (const float*)d_in[6];
  const float* b0  = (const float*)d_in[7];
  const float* gw0 = (const float*)d_in[8];
  const float* gb0 = (const float*)d_in[9];
  const float* gm0 = (const float*)d_in[10];
  const float* Wg  = (const float*)d_in[11];
  const float* asg = (const float*)d_in[12];
  const float* adg = (const float*)d_in[13];
  const float* bg  = (const float*)d_in[14];
  const float* gwg = (const float*)d_in[15];
  const float* gbg = (const float*)d_in[16];
  const float* gmg = (const float*)d_in[17];
  const float* mW0 = (const float*)d_in[18];
  const float* mb0 = (const float*)d_in[19];
  const float* lw0 = (const float*)d_in[20];
  const float* lb0 = (const float*)d_in[21];
  const float* mWg = (const float*)d_in[22];
  const float* mbg = (const float*)d_in[23];
  const float* lwg = (const float*)d_in[24];
  const float* lbg = (const float*)d_in[25];
  const float* hW  = (const float*)d_in[26];
  const float* hb  = (const float*)d_in[27];
  float* out = (float*)d_out;
  const int* src = ei;
  const int* dst = ei + N_EDGES;

  char* p = (char*)d_ws;
  auto alloc = [&](size_t bytes) {
    char* r = p;
    p += (bytes + 255) & ~(size_t)255;
    return (void*)r;
  };
  float* X   = (float*)alloc((size_t)N_NODES * 64 * 4);
  u16*   Fb  = (u16*)alloc((size_t)N_NODES * 64 * 2);
  u16*   Tb  = (u16*)alloc((size_t)N_NODES * 64 * 2);
  float* ES  = (float*)alloc((size_t)N_NODES * 4 * 4);
  float* ED  = (float*)alloc((size_t)N_NODES * 4 * 4);
  int* ssrc  = (int*)alloc((size_t)N_EDGES * 4);
  int* deg   = (int*)alloc((size_t)N_NODES * 4);
  int* off   = (int*)alloc((size_t)(N_NODES + 1) * 4);
  int* cur   = (int*)alloc((size_t)N_NODES * 4);
  int* bsum  = (int*)alloc(4096);
  int* gstart = (int*)alloc((N_GRAPHS + 1) * 4);
  u16* W0s   = (u16*)alloc((size_t)W0S_ELEMS * 2);
  u16* Wgs   = (u16*)alloc((size_t)GL * WGS_ELEMS * 2);
  float* SPp = (float*)alloc((size_t)MPART * N_GRAPHS * 64 * 4);
  float* SQp = (float*)alloc((size_t)MPART * N_GRAPHS * 64 * 4);
  float* SP  = (float*)alloc(NPART * N_GRAPHS * 64 * 4);
  float* MM  = (float*)alloc(N_GRAPHS * 64 * 4);
  float* IS  = (float*)alloc(N_GRAPHS * 64 * 4);
  (void)ws_size; (void)in_sizes; (void)n_in; (void)out_size;

  const int NB = (N_NODES + 255) / 256;
  hipMemsetAsync(deg, 0, (size_t)N_NODES * 4, stream);
  hipMemsetAsync(SPp, 0, (size_t)MPART * N_GRAPHS * 64 * 4 * 2, stream);  // SPp+SQp contiguous
  k_count_part<<<2048, 256, 0, stream>>>(dst, deg);
  k_block_sums<<<NB, 256, 0, stream>>>(deg, bsum);
  k_scan_bsums<<<1, 512, 0, stream>>>(bsum, NB, off);
  k_scan_final<<<NB, 256, 0, stream>>>(deg, bsum, off, cur);
  k_scatter_part<<<2048, 256, 0, stream>>>(src, dst, cur, ssrc);
  k_graph_starts<<<1, 32, 0, stream>>>(batch, gstart);
  k_prep_w<<<(W0S_ELEMS + GL * WGS_ELEMS + 255) / 256, 256, 0, stream>>>(W0, Wg, W0s, Wgs);

  const int GG = (N_NODES / 16 + 3) / 4;
  k_gemm0<<<GG, 256, 0, stream>>>(x, W0s, as0, ad0, Tb, ES, ED);
  for (int l = 0; l < 1 + GL; ++l) {
    const float* bl  = (l == 0) ? b0  : (bg  + (size_t)(l - 1) * 64);
    const float* gwl = (l == 0) ? gw0 : (gwg + (size_t)(l - 1) * 64);
    const float* gbl = (l == 0) ? gb0 : (gbg + (size_t)(l - 1) * 64);
    const float* gml = (l == 0) ? gm0 : (gmg + (size_t)(l - 1) * 64);
    k_edge_agg<<<N_NODES / 4, 256, 0, stream>>>(Tb, ES, ED, off, ssrc, bl, batch, Fb, SPp, SQp);
    k_stats<<<N_GRAPHS, 256, 0, stream>>>(gstart, gml, SPp, SQp, MM, IS);
    if (l < GL) {
      // fused: norm(layer l) + residual + gemm(layer l+1, weights Wg[l])
      k_norm_gemm<<<N_NODES / 16, 256, 0, stream>>>(
          Fb, batch, MM, IS, gwl, gbl,
          Wgs + (size_t)l * WGS_ELEMS, asg + (size_t)l * 64, adg + (size_t)l * 64,
          X, (l > 0) ? 1 : 0, Tb, ES, ED);
    } else {
      k_norm_res<<<(N_NODES * 64) / 1024, 256, 0, stream>>>(Fb, batch, MM, IS, gwl, gbl, X);
    }
  }

  k_moments_final<<<dim3(N_GRAPHS, NPART), 256, 0, stream>>>(X, gstart, SP, NULL);
  k_mlp<<<1, 512, 0, stream>>>(SP, gstart, gf, mW0, mb0, lw0, lb0,
                               mWg, mbg, lwg, lbg, hW, hb, out);
}

// Round 11
// 729.782 us; speedup vs baseline: 1.8889x; 1.2233x over previous
//
#include <hip/hip_runtime.h>
#include <math.h>

#define N_NODES 100000
#define N_EDGES 1200000
#define N_GRAPHS 16
#define CH 64
#define HEADS 4
#define GL 6
#define IN_DIM 261
#define GDIM 24
#define LIN 32
#define LL 3
#define EPSN 1e-5f
#define NPART 16           // final-pool moments partials
#define MPART 64           // per-layer moment partial copies
#define RNG (N_NODES / 8)  // 12500 nodes per dst-range
#define EBLK 25000         // edge_agg blocks (= N_NODES/4), 8*3125

typedef unsigned short u16;
typedef __attribute__((ext_vector_type(8))) short bf16x8;
typedef __attribute__((ext_vector_type(4))) float f32x4;

__device__ __forceinline__ u16 f2bf(float f) {
  unsigned u = __float_as_uint(f);
  u = (u + 0x7FFFu + ((u >> 16) & 1u)) >> 16;
  return (u16)u;
}
__device__ __forceinline__ float bf2f(u16 v) {
  return __uint_as_float(((unsigned)v) << 16);
}

__device__ __forceinline__ float gelu_exact(float x) {
  return 0.5f * x * (1.0f + erff(x * 0.70710678118654752440f));
}

__device__ __forceinline__ float ln32(float x, float w, float b) {
  float m = x;
  m += __shfl_xor(m, 1); m += __shfl_xor(m, 2); m += __shfl_xor(m, 4);
  m += __shfl_xor(m, 8); m += __shfl_xor(m, 16);
  m *= (1.0f / 32.0f);
  float d = x - m;
  float v = d * d;
  v += __shfl_xor(v, 1); v += __shfl_xor(v, 2); v += __shfl_xor(v, 4);
  v += __shfl_xor(v, 8); v += __shfl_xor(v, 16);
  v *= (1.0f / 32.0f);
  return d * rsqrtf(v + EPSN) * w + b;
}

// ---------------- setup: CSR build, dst-range partitioned ----------------
__global__ void k_count_part(const int* __restrict__ dst, int* __restrict__ deg) {
  const int range = blockIdx.x & 7;
  const int sub = blockIdx.x >> 3;
  const int lo = range * RNG, hi = lo + RNG;
  for (int e = sub * 256 + threadIdx.x; e < N_EDGES; e += 256 * 256) {
    int d = dst[e];
    if (d >= lo && d < hi) atomicAdd(&deg[d], 1);
  }
}

__global__ void k_scatter_part(const int* __restrict__ src, const int* __restrict__ dst,
                               int* __restrict__ cur, int* __restrict__ ssrc) {
  const int range = blockIdx.x & 7;
  const int sub = blockIdx.x >> 3;
  const int lo = range * RNG, hi = lo + RNG;
  for (int e = sub * 256 + threadIdx.x; e < N_EDGES; e += 256 * 256) {
    int d = dst[e];
    if (d >= lo && d < hi) {
      int p = atomicAdd(&cur[d], 1);
      ssrc[p] = src[e];
    }
  }
}

__global__ void k_block_sums(const int* __restrict__ deg, int* __restrict__ bsum) {
  __shared__ int sh[256];
  int i = blockIdx.x * 256 + threadIdx.x;
  sh[threadIdx.x] = (i < N_NODES) ? deg[i] : 0;
  __syncthreads();
  for (int s = 128; s > 0; s >>= 1) {
    if (threadIdx.x < s) sh[threadIdx.x] += sh[threadIdx.x + s];
    __syncthreads();
  }
  if (threadIdx.x == 0) bsum[blockIdx.x] = sh[0];
}

__global__ void k_scan_bsums(int* __restrict__ bsum, int nb, int* __restrict__ off) {
  __shared__ int sh[512];
  int i = threadIdx.x;
  int v = (i < nb) ? bsum[i] : 0;
  sh[i] = v;
  __syncthreads();
  for (int s = 1; s < 512; s <<= 1) {
    int t = (i >= s) ? sh[i - s] : 0;
    __syncthreads();
    sh[i] += t;
    __syncthreads();
  }
  if (i < nb) bsum[i] = sh[i] - v;
  if (i == nb - 1) off[N_NODES] = sh[i];
}

__global__ void k_scan_final(const int* __restrict__ deg, const int* __restrict__ bsum,
                             int* __restrict__ off, int* __restrict__ cur) {
  __shared__ int sh[256];
  int i = blockIdx.x * 256 + threadIdx.x;
  int v = (i < N_NODES) ? deg[i] : 0;
  sh[threadIdx.x] = v;
  __syncthreads();
  for (int s = 1; s < 256; s <<= 1) {
    int t = (threadIdx.x >= s) ? sh[threadIdx.x - s] : 0;
    __syncthreads();
    sh[threadIdx.x] += t;
    __syncthreads();
  }
  if (i < N_NODES) {
    int ex = bsum[blockIdx.x] + sh[threadIdx.x] - v;
    off[i] = ex;
    cur[i] = ex;
  }
}

__global__ void k_graph_starts(const int* __restrict__ batch, int* __restrict__ gstart) {
  int g = threadIdx.x;
  if (g > N_GRAPHS) return;
  int lo = 0, hi = N_NODES;
  while (lo < hi) {
    int mid = (lo + hi) >> 1;
    if (batch[mid] < g) lo = mid + 1; else hi = mid;
  }
  gstart[g] = lo;
}

// ---------------- weight prep: fp32 -> bf16 B-fragment swizzle ----------------
#define W0S_ELEMS (4 * 9 * 64 * 8)
#define WGS_ELEMS (4 * 2 * 64 * 8)
__global__ void k_prep_w(const float* __restrict__ W0, const float* __restrict__ Wg,
                         u16* __restrict__ W0s, u16* __restrict__ Wgs) {
  int idx = blockIdx.x * 256 + threadIdx.x;
  if (idx < W0S_ELEMS) {
    int i = idx & 7, lane = (idx >> 3) & 63, ks = (idx >> 9) % 9, cb = idx / (9 * 512);
    int k = ks * 32 + (lane >> 4) * 8 + i, c = cb * 16 + (lane & 15);
    W0s[idx] = f2bf(k < IN_DIM ? W0[k * 64 + c] : 0.f);
  } else if (idx < W0S_ELEMS + GL * WGS_ELEMS) {
    int j = idx - W0S_ELEMS;
    int l = j / WGS_ELEMS, p = j % WGS_ELEMS;
    int i = p & 7, lane = (p >> 3) & 63, ks = (p >> 9) & 1, cb = p / (2 * 512);
    int k = ks * 32 + (lane >> 4) * 8 + i, c = cb * 16 + (lane & 15);
    Wgs[j] = f2bf(Wg[(size_t)l * 4096 + k * 64 + c]);
  }
}

// ---------------- layer 0: standalone MFMA GEMM + logits ----------------
__global__ __launch_bounds__(256) void k_gemm0(
    const float* __restrict__ Xin, const u16* __restrict__ Wswz,
    const float* __restrict__ a_src, const float* __restrict__ a_dst,
    u16* __restrict__ Tb, float* __restrict__ ES, float* __restrict__ ED) {
  const int lane = threadIdx.x & 63;
  const int wid = (blockIdx.x << 2) + (threadIdx.x >> 6);
  const int NT = N_NODES / 16;
  if (wid >= NT) return;
  const int grp = lane >> 4, n16 = lane & 15;
  float as_l[4], ad_l[4];
  #pragma unroll
  for (int cb = 0; cb < 4; ++cb) {
    as_l[cb] = a_src[cb * 16 + n16];
    ad_l[cb] = a_dst[cb * 16 + n16];
  }
  const long r0 = (long)wid * 16;

  bf16x8 afr[9];
  const float* xr = Xin + (r0 + n16) * (size_t)IN_DIM;
  #pragma unroll
  for (int ks = 0; ks < 9; ++ks) {
    bf16x8 a;
    #pragma unroll
    for (int i = 0; i < 8; ++i) {
      int k = ks * 32 + grp * 8 + i;
      float v = (k < IN_DIM) ? xr[k] : 0.f;
      a[i] = (short)f2bf(v);
    }
    afr[ks] = a;
  }

  #pragma unroll
  for (int cb = 0; cb < 4; ++cb) {
    f32x4 a = {0.f, 0.f, 0.f, 0.f};
    #pragma unroll
    for (int ks = 0; ks < 9; ++ks) {
      bf16x8 b = *(const bf16x8*)(Wswz + ((size_t)(cb * 9 + ks) * 64 + lane) * 8);
      a = __builtin_amdgcn_mfma_f32_16x16x32_bf16(afr[ks], b, a, 0, 0, 0);
    }
    #pragma unroll
    for (int r = 0; r < 4; ++r) {
      const long row = r0 + grp * 4 + r;
      float v = a[r];
      Tb[row * 64 + cb * 16 + n16] = f2bf(v);
      float s = v * as_l[cb];
      float d = v * ad_l[cb];
      s += __shfl_xor(s, 1); s += __shfl_xor(s, 2); s += __shfl_xor(s, 4); s += __shfl_xor(s, 8);
      d += __shfl_xor(d, 1); d += __shfl_xor(d, 2); d += __shfl_xor(d, 4); d += __shfl_xor(d, 8);
      if (n16 == 0) {
        ES[row * 4 + cb] = s;
        ED[row * 4 + cb] = d;
      }
    }
  }
}

// ---------------- edge softmax + aggregate + LDS-reduced moment partials ----------------
__global__ __launch_bounds__(256) void k_edge_agg(
    const u16* __restrict__ Tb, const float* __restrict__ ES, const float* __restrict__ ED,
    const int* __restrict__ off, const int* __restrict__ ssrc,
    const float* __restrict__ bias, const int* __restrict__ batch,
    u16* __restrict__ Fb, float* __restrict__ SPp, float* __restrict__ SQp) {
  __shared__ float sF[4][64];
  __shared__ float sQ[4][64];
  const int lane = threadIdx.x & 63;
  const int wv = threadIdx.x >> 6;
  // XCD-chunked swizzle: 25000 blocks = 8 * 3125, each XCD gets a contiguous dst range
  const int bid = (blockIdx.x & 7) * (EBLK / 8) + (blockIdx.x >> 3);
  const int n = bid * 4 + wv;
  const int e0 = off[n];
  const int ec = off[n + 1] - e0;
  const int hd = lane & 3;
  const int qh = lane >> 4;
  const u16* Tl = Tb + lane;
  const float tself = bf2f(Tl[(long)n * 64]);   // issue early
  const float ed_h = ED[n * 4 + hd];
  float x0 = ES[n * 4 + hd] + ed_h;
  x0 = fmaxf(x0, 0.2f * x0);
  const float p0 = __expf(fminf(x0, 25.f));
  float s_run = p0;
  float acc = __shfl(p0, qh) * tself;
  for (int base = 0; base < ec; base += 16) {
    const int eidx = base + (lane >> 2);
    const bool valid = eidx < ec;
    const int sv = valid ? ssrc[e0 + eidx] : n;
    int rows[16];
    #pragma unroll
    for (int e = 0; e < 16; ++e) rows[e] = __shfl(sv, e << 2);
    float tv[16];
    #pragma unroll
    for (int e = 0; e < 16; ++e) tv[e] = bf2f(Tl[(long)rows[e] * 64]);
    float v = ES[sv * 4 + hd] + ed_h;
    v = fmaxf(v, 0.2f * v);
    const float p = valid ? __expf(fminf(v, 25.f)) : 0.f;
    float ps = p;
    ps += __shfl_xor(ps, 4); ps += __shfl_xor(ps, 8);
    ps += __shfl_xor(ps, 16); ps += __shfl_xor(ps, 32);
    s_run += ps;
    #pragma unroll
    for (int e = 0; e < 16; ++e)
      acc = fmaf(__shfl(p, (e << 2) | qh), tv[e], acc);
  }
  const float s_q = __shfl(s_run, qh);
  const float o = acc / (s_q + 1e-16f) + bias[lane];
  const float f = gelu_exact(o);
  Fb[(long)n * 64 + lane] = f2bf(f);
  sF[wv][lane] = f;
  sQ[wv][lane] = f * f;
  __syncthreads();
  // per-block LDS reduce, flush one atomic pair per graph-run (typically 1 run)
  if (threadIdx.x < 64) {
    const int part = bid & (MPART - 1);
    const long nb = (long)bid * 4;
    int gprev = batch[nb];
    float fs = 0.f, qs = 0.f;
    #pragma unroll
    for (int w2 = 0; w2 < 4; ++w2) {
      int gw = batch[nb + w2];
      if (gw != gprev) {
        atomicAdd(&SPp[((size_t)part * N_GRAPHS + gprev) * 64 + threadIdx.x], fs);
        atomicAdd(&SQp[((size_t)part * N_GRAPHS + gprev) * 64 + threadIdx.x], qs);
        fs = 0.f; qs = 0.f; gprev = gw;
      }
      fs += sF[w2][threadIdx.x];
      qs += sQ[w2][threadIdx.x];
    }
    atomicAdd(&SPp[((size_t)part * N_GRAPHS + gprev) * 64 + threadIdx.x], fs);
    atomicAdd(&SQp[((size_t)part * N_GRAPHS + gprev) * 64 + threadIdx.x], qs);
  }
}

// ---------------- per-layer stats: reduce partials -> MM/IS, re-zero ----------------
__global__ void k_stats(const int* __restrict__ gstart, const float* __restrict__ ms,
                        float* __restrict__ SPp, float* __restrict__ SQp,
                        float* __restrict__ MM, float* __restrict__ IS) {
  const int g = blockIdx.x;
  const int t = threadIdx.x;         // 256
  const int c = t & 63, chunk = t >> 6;
  float s = 0.f, q = 0.f;
  for (int p2 = chunk * 16; p2 < chunk * 16 + 16; ++p2) {
    s += SPp[((size_t)p2 * N_GRAPHS + g) * 64 + c];
    q += SQp[((size_t)p2 * N_GRAPHS + g) * 64 + c];
  }
  __shared__ float ls[4][64];
  __shared__ float lq[4][64];
  ls[chunk][c] = s;
  lq[chunk][c] = q;
  __syncthreads();
  if (t < 64) {
    s = ls[0][t] + ls[1][t] + ls[2][t] + ls[3][t];
    q = lq[0][t] + lq[1][t] + lq[2][t] + lq[3][t];
    float cnt = fmaxf((float)(gstart[g + 1] - gstart[g]), 1.0f);
    float mean = s / cnt;
    float mm = mean * ms[t];
    float var = q / cnt - 2.f * mm * mean + mm * mm;
    MM[g * 64 + t] = mm;
    IS[g * 64 + t] = rsqrtf(fmaxf(var, 0.f) + EPSN);
  }
  __syncthreads();
  for (int p2 = chunk * 16; p2 < chunk * 16 + 16; ++p2) {
    SPp[((size_t)p2 * N_GRAPHS + g) * 64 + c] = 0.f;
    SQp[((size_t)p2 * N_GRAPHS + g) * 64 + c] = 0.f;
  }
}

// ---------------- fused: GraphNorm + residual + NEXT layer's GEMM + logits ----------------
__global__ __launch_bounds__(256) void k_norm_gemm(
    const u16* __restrict__ Fb, const int* __restrict__ batch,
    const float* __restrict__ MM, const float* __restrict__ IS,
    const float* __restrict__ w, const float* __restrict__ b,
    const u16* __restrict__ Wswz, const float* __restrict__ a_src,
    const float* __restrict__ a_dst, float* __restrict__ X, int residual,
    u16* __restrict__ Tb, float* __restrict__ ES, float* __restrict__ ED) {
  __shared__ __align__(16) u16 sY[16][72];   // 144B rows: 16B-aligned
  const int tid = threadIdx.x;
  const long n0 = (long)blockIdx.x * 16;
  {
    const int node = tid >> 4;
    const int c4 = (tid & 15) << 2;
    const long n = n0 + node;
    const int g = batch[n];
    ushort4 fu = *(const ushort4*)(Fb + n * 64 + c4);
    float4 f = make_float4(bf2f(fu.x), bf2f(fu.y), bf2f(fu.z), bf2f(fu.w));
    float4 mm = *(const float4*)(MM + g * 64 + c4);
    float4 is = *(const float4*)(IS + g * 64 + c4);
    float4 wv = *(const float4*)(w + c4);
    float4 bv = *(const float4*)(b + c4);
    float4 y;
    y.x = fmaf(wv.x * (f.x - mm.x), is.x, bv.x);
    y.y = fmaf(wv.y * (f.y - mm.y), is.y, bv.y);
    y.z = fmaf(wv.z * (f.z - mm.z), is.z, bv.z);
    y.w = fmaf(wv.w * (f.w - mm.w), is.w, bv.w);
    float4* xp = (float4*)(X + n * 64 + c4);
    if (residual) {
      float4 xo = *xp;
      y.x += xo.x; y.y += xo.y; y.z += xo.z; y.w += xo.w;
    }
    *xp = y;
    union { u16 s[4]; unsigned long long ll; } pk;
    pk.s[0] = f2bf(y.x); pk.s[1] = f2bf(y.y); pk.s[2] = f2bf(y.z); pk.s[3] = f2bf(y.w);
    *(unsigned long long*)&sY[node][c4] = pk.ll;
  }
  __syncthreads();
  const int lane = tid & 63;
  const int wid = tid >> 6;
  const int grp = lane >> 4, n16 = lane & 15;
  bf16x8 afr[2];
  #pragma unroll
  for (int ks = 0; ks < 2; ++ks)
    afr[ks] = *(const bf16x8*)(&sY[n16][ks * 32 + grp * 8]);
  f32x4 a = {0.f, 0.f, 0.f, 0.f};
  #pragma unroll
  for (int ks = 0; ks < 2; ++ks) {
    bf16x8 bb = *(const bf16x8*)(Wswz + ((size_t)(wid * 2 + ks) * 64 + lane) * 8);
    a = __builtin_amdgcn_mfma_f32_16x16x32_bf16(afr[ks], bb, a, 0, 0, 0);
  }
  const float as_c = a_src[wid * 16 + n16];
  const float ad_c = a_dst[wid * 16 + n16];
  #pragma unroll
  for (int r = 0; r < 4; ++r) {
    const long row = n0 + grp * 4 + r;
    float v = a[r];
    Tb[row * 64 + wid * 16 + n16] = f2bf(v);
    float s = v * as_c;
    float d = v * ad_c;
    s += __shfl_xor(s, 1); s += __shfl_xor(s, 2); s += __shfl_xor(s, 4); s += __shfl_xor(s, 8);
    d += __shfl_xor(d, 1); d += __shfl_xor(d, 2); d += __shfl_xor(d, 4); d += __shfl_xor(d, 8);
    if (n16 == 0) {
      ES[row * 4 + wid] = s;
      ED[row * 4 + wid] = d;
    }
  }
}

// ---------------- last layer: plain norm + residual ----------------
__global__ void k_norm_res(const u16* __restrict__ Fb, const int* __restrict__ batch,
                           const float* __restrict__ MM, const float* __restrict__ IS,
                           const float* __restrict__ w, const float* __restrict__ b,
                           float* __restrict__ X) {
  const long i4 = (long)blockIdx.x * 256 + threadIdx.x;
  const int n = (int)(i4 >> 4);
  const int c4 = (int)(i4 & 15) << 2;
  const int g = batch[n];
  ushort4 fu = *(const ushort4*)(Fb + i4 * 4);
  float4 f = make_float4(bf2f(fu.x), bf2f(fu.y), bf2f(fu.z), bf2f(fu.w));
  float4 mm = *(const float4*)(MM + g * 64 + c4);
  float4 is = *(const float4*)(IS + g * 64 + c4);
  float4 wv = *(const float4*)(w + c4);
  float4 bv = *(const float4*)(b + c4);
  float4 y;
  y.x = fmaf(wv.x * (f.x - mm.x), is.x, bv.x);
  y.y = fmaf(wv.y * (f.y - mm.y), is.y, bv.y);
  y.z = fmaf(wv.z * (f.z - mm.z), is.z, bv.z);
  y.w = fmaf(wv.w * (f.w - mm.w), is.w, bv.w);
  float4* xp = (float4*)(X + i4 * 4);
  float4 xo = *xp;
  y.x += xo.x; y.y += xo.y; y.z += xo.z; y.w += xo.w;
  *xp = y;
}

// ---------------- final pooling moments (fp32 X, 16 partials) ----------------
__global__ void k_moments_final(const float* __restrict__ X, const int* __restrict__ gstart,
                                float* __restrict__ SP) {
  const int g = blockIdx.x;
  const int s0 = gstart[g];
  const int rows = gstart[g + 1] - s0;
  const int lane = threadIdx.x & 63;
  const int w = threadIdx.x >> 6;
  float sum = 0.f;
  for (int r = blockIdx.y * 4 + w; r < rows; r += gridDim.y * 4)
    sum += X[(long)(s0 + r) * 64 + lane];
  __shared__ float ls[4][64];
  ls[w][lane] = sum;
  __syncthreads();
  if (threadIdx.x < 64) {
    float a = ls[0][lane] + ls[1][lane] + ls[2][lane] + ls[3][lane];
    SP[(blockIdx.y * N_GRAPHS + g) * 64 + lane] = a;
  }
}

// ---------------- pooled MLP head (one block) ----------------
__global__ __launch_bounds__(512) void k_mlp(
    const float* __restrict__ SP, const int* __restrict__ gstart, const float* __restrict__ gf,
    const float* __restrict__ W0, const float* __restrict__ b0,
    const float* __restrict__ lw0, const float* __restrict__ lb0,
    const float* __restrict__ Wg, const float* __restrict__ bg,
    const float* __restrict__ lwg, const float* __restrict__ lbg,
    const float* __restrict__ hW, const float* __restrict__ hb,
    float* __restrict__ out) {
  __shared__ float P[16][88];
  __shared__ float Z[16][32];
  const int tid = threadIdx.x;
  for (int i = tid; i < 16 * 88; i += 512) {
    int g = i / 88, c = i - g * 88;
    float v;
    if (c < 64) {
      float s = 0.f;
      #pragma unroll
      for (int b = 0; b < NPART; ++b) s += SP[(b * N_GRAPHS + g) * 64 + c];
      float cnt = fmaxf((float)(gstart[g + 1] - gstart[g]), 1.0f);
      v = s / cnt;
    } else {
      v = gf[g * GDIM + (c - 64)];
    }
    P[g][c] = v;
  }
  __syncthreads();
  const int g = tid >> 5, c = tid & 31;
  float acc = b0[c];
  for (int k = 0; k < 88; ++k) acc = fmaf(P[g][k], W0[k * 32 + c], acc);
  float z = ln32(gelu_exact(acc), lw0[c], lb0[c]);
  for (int l = 0; l < LL; ++l) {
    Z[g][c] = z;
    __syncthreads();
    float a2 = bg[l * 32 + c];
    const float* Wl = Wg + l * 32 * 32;
    for (int k = 0; k < 32; ++k) a2 = fmaf(Z[g][k], Wl[k * 32 + c], a2);
    __syncthreads();
    z = ln32(gelu_exact(a2), lwg[l * 32 + c], lbg[l * 32 + c]) + z;
  }
  Z[g][c] = z * hW[c];
  __syncthreads();
  if (c == 0) {
    float s = 0.f;
    for (int k = 0; k < 32; ++k) s += Z[g][k];
    out[g] = s + hb[0];
  }
}

extern "C" void kernel_launch(void* const* d_in, const int* in_sizes, int n_in,
                              void* d_out, int out_size, void* d_ws, size_t ws_size,
                              hipStream_t stream) {
  const float* x   = (const float*)d_in[0];
  const int*   ei  = (const int*)d_in[1];
  const int* batch = (const int*)d_in[2];
  const float* gf  = (const float*)d_in[3];
  const float* W0  = (const float*)d_in[4];
  const float* as0 = (const float*)d_in[5];
  const float* ad0 = (const float*)d_in[6];
  const float* b0  = (const float*)d_in[7];
  const float* gw0 = (const float*)d_in[8];
  const float* gb0 = (const float*)d_in[9];
  const float* gm0 = (const float*)d_in[10];
  const float* Wg  = (const float*)d_in[11];
  const float* asg = (const float*)d_in[12];
  const float* adg = (const float*)d_in[13];
  const float* bg  = (const float*)d_in[14];
  const float* gwg = (const float*)d_in[15];
  const float* gbg = (const float*)d_in[16];
  const float* gmg = (const float*)d_in[17];
  const float* mW0 = (const float*)d_in[18];
  const float* mb0 = (const float*)d_in[19];
  const float* lw0 = (const float*)d_in[20];
  const float* lb0 = (const float*)d_in[21];
  const float* mWg = (const float*)d_in[22];
  const float* mbg = (const float*)d_in[23];
  const float* lwg = (const float*)d_in[24];
  const float* lbg = (const float*)d_in[25];
  const float* hW  = (const float*)d_in[26];
  const float* hb  = (const float*)d_in[27];
  float* out = (float*)d_out;
  const int* src = ei;
  const int* dst = ei + N_EDGES;

  char* p = (char*)d_ws;
  auto alloc = [&](size_t bytes) {
    char* r = p;
    p += (bytes + 255) & ~(size_t)255;
    return (void*)r;
  };
  float* X   = (float*)alloc((size_t)N_NODES * 64 * 4);
  u16*   Fb  = (u16*)alloc((size_t)N_NODES * 64 * 2);
  u16*   Tb  = (u16*)alloc((size_t)N_NODES * 64 * 2);
  float* ES  = (float*)alloc((size_t)N_NODES * 4 * 4);
  float* ED  = (float*)alloc((size_t)N_NODES * 4 * 4);
  int* ssrc  = (int*)alloc((size_t)N_EDGES * 4);
  int* deg   = (int*)alloc((size_t)N_NODES * 4);
  int* off   = (int*)alloc((size_t)(N_NODES + 1) * 4);
  int* cur   = (int*)alloc((size_t)N_NODES * 4);
  int* bsum  = (int*)alloc(4096);
  int* gstart = (int*)alloc((N_GRAPHS + 1) * 4);
  u16* W0s   = (u16*)alloc((size_t)W0S_ELEMS * 2);
  u16* Wgs   = (u16*)alloc((size_t)GL * WGS_ELEMS * 2);
  float* SPp = (float*)alloc((size_t)MPART * N_GRAPHS * 64 * 4);
  float* SQp = (float*)alloc((size_t)MPART * N_GRAPHS * 64 * 4);
  float* SP  = (float*)alloc(NPART * N_GRAPHS * 64 * 4);
  float* MM  = (float*)alloc(N_GRAPHS * 64 * 4);
  float* IS  = (float*)alloc(N_GRAPHS * 64 * 4);
  (void)ws_size; (void)in_sizes; (void)n_in; (void)out_size;

  const int NB = (N_NODES + 255) / 256;
  hipMemsetAsync(deg, 0, (size_t)N_NODES * 4, stream);
  hipMemsetAsync(SPp, 0, (size_t)MPART * N_GRAPHS * 64 * 4 * 2, stream);  // SPp+SQp contiguous
  k_count_part<<<2048, 256, 0, stream>>>(dst, deg);
  k_block_sums<<<NB, 256, 0, stream>>>(deg, bsum);
  k_scan_bsums<<<1, 512, 0, stream>>>(bsum, NB, off);
  k_scan_final<<<NB, 256, 0, stream>>>(deg, bsum, off, cur);
  k_scatter_part<<<2048, 256, 0, stream>>>(src, dst, cur, ssrc);
  k_graph_starts<<<1, 32, 0, stream>>>(batch, gstart);
  k_prep_w<<<(W0S_ELEMS + GL * WGS_ELEMS + 255) / 256, 256, 0, stream>>>(W0, Wg, W0s, Wgs);

  const int GG = (N_NODES / 16 + 3) / 4;
  k_gemm0<<<GG, 256, 0, stream>>>(x, W0s, as0, ad0, Tb, ES, ED);
  for (int l = 0; l < 1 + GL; ++l) {
    const float* bl  = (l == 0) ? b0  : (bg  + (size_t)(l - 1) * 64);
    const float* gwl = (l == 0) ? gw0 : (gwg + (size_t)(l - 1) * 64);
    const float* gbl = (l == 0) ? gb0 : (gbg + (size_t)(l - 1) * 64);
    const float* gml = (l == 0) ? gm0 : (gmg + (size_t)(l - 1) * 64);
    k_edge_agg<<<EBLK, 256, 0, stream>>>(Tb, ES, ED, off, ssrc, bl, batch, Fb, SPp, SQp);
    k_stats<<<N_GRAPHS, 256, 0, stream>>>(gstart, gml, SPp, SQp, MM, IS);
    if (l < GL) {
      k_norm_gemm<<<N_NODES / 16, 256, 0, stream>>>(
          Fb, batch, MM, IS, gwl, gbl,
          Wgs + (size_t)l * WGS_ELEMS, asg + (size_t)l * 64, adg + (size_t)l * 64,
          X, (l > 0) ? 1 : 0, Tb, ES, ED);
    } else {
      k_norm_res<<<(N_NODES * 64) / 1024, 256, 0, stream>>>(Fb, batch, MM, IS, gwl, gbl, X);
    }
  }

  k_moments_final<<<dim3(N_GRAPHS, NPART), 256, 0, stream>>>(X, gstart, SP);
  k_mlp<<<1, 512, 0, stream>>>(SP, gstart, gf, mW0, mb0, lw0, lb0,
                               mWg, mbg, lwg, lbg, hW, hb, out);
}

// Round 12
// 719.457 us; speedup vs baseline: 1.9160x; 1.0144x over previous
//
#include <hip/hip_runtime.h>
#include <math.h>

#define N_NODES 100000
#define N_EDGES 1200000
#define N_GRAPHS 16
#define CH 64
#define HEADS 4
#define GL 6
#define IN_DIM 261
#define GDIM 24
#define LIN 32
#define LL 3
#define EPSN 1e-5f
#define NPART 16           // final-pool moments partials
#define MPART 64           // per-layer moment partial copies
#define RNG (N_NODES / 8)  // 12500 nodes per dst-range
#define EBLK 25000         // edge_agg blocks (= N_NODES/4), 8*3125

typedef unsigned short u16;
typedef unsigned char u8;
typedef __attribute__((ext_vector_type(8))) short bf16x8;
typedef __attribute__((ext_vector_type(4))) float f32x4;

__device__ __forceinline__ u16 f2bf(float f) {
  unsigned u = __float_as_uint(f);
  u = (u + 0x7FFFu + ((u >> 16) & 1u)) >> 16;
  return (u16)u;
}
__device__ __forceinline__ float bf2f(u16 v) {
  return __uint_as_float(((unsigned)v) << 16);
}
// OCP e4m3 via gfx950 HW converts
__device__ __forceinline__ u8 f2fp8(float f) {
  int r = __builtin_amdgcn_cvt_pk_fp8_f32(f, f, 0, false);
  return (u8)(r & 0xff);
}
__device__ __forceinline__ float fp82f(int b) {
  return __builtin_amdgcn_cvt_f32_fp8(b, 0);
}

__device__ __forceinline__ float gelu_exact(float x) {
  return 0.5f * x * (1.0f + erff(x * 0.70710678118654752440f));
}

__device__ __forceinline__ float ln32(float x, float w, float b) {
  float m = x;
  m += __shfl_xor(m, 1); m += __shfl_xor(m, 2); m += __shfl_xor(m, 4);
  m += __shfl_xor(m, 8); m += __shfl_xor(m, 16);
  m *= (1.0f / 32.0f);
  float d = x - m;
  float v = d * d;
  v += __shfl_xor(v, 1); v += __shfl_xor(v, 2); v += __shfl_xor(v, 4);
  v += __shfl_xor(v, 8); v += __shfl_xor(v, 16);
  v *= (1.0f / 32.0f);
  return d * rsqrtf(v + EPSN) * w + b;
}

// ---------------- setup: CSR build, dst-range partitioned ----------------
__global__ void k_count_part(const int* __restrict__ dst, int* __restrict__ deg) {
  const int range = blockIdx.x & 7;
  const int sub = blockIdx.x >> 3;
  const int lo = range * RNG, hi = lo + RNG;
  for (int e = sub * 256 + threadIdx.x; e < N_EDGES; e += 256 * 256) {
    int d = dst[e];
    if (d >= lo && d < hi) atomicAdd(&deg[d], 1);
  }
}

__global__ void k_scatter_part(const int* __restrict__ src, const int* __restrict__ dst,
                               int* __restrict__ cur, int* __restrict__ ssrc) {
  const int range = blockIdx.x & 7;
  const int sub = blockIdx.x >> 3;
  const int lo = range * RNG, hi = lo + RNG;
  for (int e = sub * 256 + threadIdx.x; e < N_EDGES; e += 256 * 256) {
    int d = dst[e];
    if (d >= lo && d < hi) {
      int p = atomicAdd(&cur[d], 1);
      ssrc[p] = src[e];
    }
  }
}

__global__ void k_block_sums(const int* __restrict__ deg, int* __restrict__ bsum) {
  __shared__ int sh[256];
  int i = blockIdx.x * 256 + threadIdx.x;
  sh[threadIdx.x] = (i < N_NODES) ? deg[i] : 0;
  __syncthreads();
  for (int s = 128; s > 0; s >>= 1) {
    if (threadIdx.x < s) sh[threadIdx.x] += sh[threadIdx.x + s];
    __syncthreads();
  }
  if (threadIdx.x == 0) bsum[blockIdx.x] = sh[0];
}

__global__ void k_scan_bsums(int* __restrict__ bsum, int nb, int* __restrict__ off) {
  __shared__ int sh[512];
  int i = threadIdx.x;
  int v = (i < nb) ? bsum[i] : 0;
  sh[i] = v;
  __syncthreads();
  for (int s = 1; s < 512; s <<= 1) {
    int t = (i >= s) ? sh[i - s] : 0;
    __syncthreads();
    sh[i] += t;
    __syncthreads();
  }
  if (i < nb) bsum[i] = sh[i] - v;
  if (i == nb - 1) off[N_NODES] = sh[i];
}

__global__ void k_scan_final(const int* __restrict__ deg, const int* __restrict__ bsum,
                             int* __restrict__ off, int* __restrict__ cur) {
  __shared__ int sh[256];
  int i = blockIdx.x * 256 + threadIdx.x;
  int v = (i < N_NODES) ? deg[i] : 0;
  sh[threadIdx.x] = v;
  __syncthreads();
  for (int s = 1; s < 256; s <<= 1) {
    int t = (threadIdx.x >= s) ? sh[threadIdx.x - s] : 0;
    __syncthreads();
    sh[threadIdx.x] += t;
    __syncthreads();
  }
  if (i < N_NODES) {
    int ex = bsum[blockIdx.x] + sh[threadIdx.x] - v;
    off[i] = ex;
    cur[i] = ex;
  }
}

__global__ void k_graph_starts(const int* __restrict__ batch, int* __restrict__ gstart) {
  int g = threadIdx.x;
  if (g > N_GRAPHS) return;
  int lo = 0, hi = N_NODES;
  while (lo < hi) {
    int mid = (lo + hi) >> 1;
    if (batch[mid] < g) lo = mid + 1; else hi = mid;
  }
  gstart[g] = lo;
}

// ---------------- weight prep: fp32 -> bf16 B-fragment swizzle ----------------
#define W0S_ELEMS (4 * 9 * 64 * 8)
#define WGS_ELEMS (4 * 2 * 64 * 8)
__global__ void k_prep_w(const float* __restrict__ W0, const float* __restrict__ Wg,
                         u16* __restrict__ W0s, u16* __restrict__ Wgs) {
  int idx = blockIdx.x * 256 + threadIdx.x;
  if (idx < W0S_ELEMS) {
    int i = idx & 7, lane = (idx >> 3) & 63, ks = (idx >> 9) % 9, cb = idx / (9 * 512);
    int k = ks * 32 + (lane >> 4) * 8 + i, c = cb * 16 + (lane & 15);
    W0s[idx] = f2bf(k < IN_DIM ? W0[k * 64 + c] : 0.f);
  } else if (idx < W0S_ELEMS + GL * WGS_ELEMS) {
    int j = idx - W0S_ELEMS;
    int l = j / WGS_ELEMS, p = j % WGS_ELEMS;
    int i = p & 7, lane = (p >> 3) & 63, ks = (p >> 9) & 1, cb = p / (2 * 512);
    int k = ks * 32 + (lane >> 4) * 8 + i, c = cb * 16 + (lane & 15);
    Wgs[j] = f2bf(Wg[(size_t)l * 4096 + k * 64 + c]);
  }
}

// ---------------- layer 0: standalone MFMA GEMM + logits (fp8 T out) ----------------
__global__ __launch_bounds__(256) void k_gemm0(
    const float* __restrict__ Xin, const u16* __restrict__ Wswz,
    const float* __restrict__ a_src, const float* __restrict__ a_dst,
    u8* __restrict__ T8, float* __restrict__ ES, float* __restrict__ ED) {
  const int lane = threadIdx.x & 63;
  const int wid = (blockIdx.x << 2) + (threadIdx.x >> 6);
  const int NT = N_NODES / 16;
  if (wid >= NT) return;
  const int grp = lane >> 4, n16 = lane & 15;
  float as_l[4], ad_l[4];
  #pragma unroll
  for (int cb = 0; cb < 4; ++cb) {
    as_l[cb] = a_src[cb * 16 + n16];
    ad_l[cb] = a_dst[cb * 16 + n16];
  }
  const long r0 = (long)wid * 16;

  bf16x8 afr[9];
  const float* xr = Xin + (r0 + n16) * (size_t)IN_DIM;
  #pragma unroll
  for (int ks = 0; ks < 9; ++ks) {
    bf16x8 a;
    #pragma unroll
    for (int i = 0; i < 8; ++i) {
      int k = ks * 32 + grp * 8 + i;
      float v = (k < IN_DIM) ? xr[k] : 0.f;
      a[i] = (short)f2bf(v);
    }
    afr[ks] = a;
  }

  #pragma unroll
  for (int cb = 0; cb < 4; ++cb) {
    f32x4 a = {0.f, 0.f, 0.f, 0.f};
    #pragma unroll
    for (int ks = 0; ks < 9; ++ks) {
      bf16x8 b = *(const bf16x8*)(Wswz + ((size_t)(cb * 9 + ks) * 64 + lane) * 8);
      a = __builtin_amdgcn_mfma_f32_16x16x32_bf16(afr[ks], b, a, 0, 0, 0);
    }
    #pragma unroll
    for (int r = 0; r < 4; ++r) {
      const long row = r0 + grp * 4 + r;
      float v = a[r];
      T8[row * 64 + cb * 16 + n16] = f2fp8(v);
      float s = v * as_l[cb];
      float d = v * ad_l[cb];
      s += __shfl_xor(s, 1); s += __shfl_xor(s, 2); s += __shfl_xor(s, 4); s += __shfl_xor(s, 8);
      d += __shfl_xor(d, 1); d += __shfl_xor(d, 2); d += __shfl_xor(d, 4); d += __shfl_xor(d, 8);
      if (n16 == 0) {
        ES[row * 4 + cb] = s;
        ED[row * 4 + cb] = d;
      }
    }
  }
}

// ---------------- edge softmax + aggregate (fp8 T gathers) + moment partials ----------------
__global__ __launch_bounds__(256) void k_edge_agg(
    const u8* __restrict__ T8, const float* __restrict__ ES, const float* __restrict__ ED,
    const int* __restrict__ off, const int* __restrict__ ssrc,
    const float* __restrict__ bias, const int* __restrict__ batch,
    u16* __restrict__ Fb, float* __restrict__ SPp, float* __restrict__ SQp) {
  __shared__ float sF[4][64];
  __shared__ float sQ[4][64];
  const int lane = threadIdx.x & 63;
  const int wv = threadIdx.x >> 6;
  // XCD-chunked swizzle: 25000 blocks = 8 * 3125
  const int bid = (blockIdx.x & 7) * (EBLK / 8) + (blockIdx.x >> 3);
  const int n = bid * 4 + wv;
  const int e0 = off[n];
  const int ec = off[n + 1] - e0;
  const int hd = lane & 3;
  const int qh = lane >> 4;
  const u8* Tl = T8 + lane;
  const float tself = fp82f(Tl[(long)n * 64]);   // issue early
  const float ed_h = ED[n * 4 + hd];
  float x0 = ES[n * 4 + hd] + ed_h;
  x0 = fmaxf(x0, 0.2f * x0);
  const float p0 = __expf(fminf(x0, 25.f));
  float s_run = p0;
  float acc = __shfl(p0, qh) * tself;
  for (int base = 0; base < ec; base += 16) {
    const int eidx = base + (lane >> 2);
    const bool valid = eidx < ec;
    const int sv = valid ? ssrc[e0 + eidx] : n;
    int rows[16];
    #pragma unroll
    for (int e = 0; e < 16; ++e) rows[e] = __shfl(sv, e << 2);
    int tvb[16];
    #pragma unroll
    for (int e = 0; e < 16; ++e) tvb[e] = Tl[(long)rows[e] * 64];
    float v = ES[sv * 4 + hd] + ed_h;
    v = fmaxf(v, 0.2f * v);
    const float p = valid ? __expf(fminf(v, 25.f)) : 0.f;
    float ps = p;
    ps += __shfl_xor(ps, 4); ps += __shfl_xor(ps, 8);
    ps += __shfl_xor(ps, 16); ps += __shfl_xor(ps, 32);
    s_run += ps;
    #pragma unroll
    for (int e = 0; e < 16; ++e)
      acc = fmaf(__shfl(p, (e << 2) | qh), fp82f(tvb[e]), acc);
  }
  const float s_q = __shfl(s_run, qh);
  const float o = acc / (s_q + 1e-16f) + bias[lane];
  const float f = gelu_exact(o);
  Fb[(long)n * 64 + lane] = f2bf(f);
  sF[wv][lane] = f;
  sQ[wv][lane] = f * f;
  __syncthreads();
  if (threadIdx.x < 64) {
    const int part = bid & (MPART - 1);
    const long nb = (long)bid * 4;
    int gprev = batch[nb];
    float fs = 0.f, qs = 0.f;
    #pragma unroll
    for (int w2 = 0; w2 < 4; ++w2) {
      int gw = batch[nb + w2];
      if (gw != gprev) {
        atomicAdd(&SPp[((size_t)part * N_GRAPHS + gprev) * 64 + threadIdx.x], fs);
        atomicAdd(&SQp[((size_t)part * N_GRAPHS + gprev) * 64 + threadIdx.x], qs);
        fs = 0.f; qs = 0.f; gprev = gw;
      }
      fs += sF[w2][threadIdx.x];
      qs += sQ[w2][threadIdx.x];
    }
    atomicAdd(&SPp[((size_t)part * N_GRAPHS + gprev) * 64 + threadIdx.x], fs);
    atomicAdd(&SQp[((size_t)part * N_GRAPHS + gprev) * 64 + threadIdx.x], qs);
  }
}

// ---------------- per-layer stats: reduce partials -> MM/IS, re-zero ----------------
__global__ void k_stats(const int* __restrict__ gstart, const float* __restrict__ ms,
                        float* __restrict__ SPp, float* __restrict__ SQp,
                        float* __restrict__ MM, float* __restrict__ IS) {
  const int g = blockIdx.x;
  const int t = threadIdx.x;         // 256
  const int c = t & 63, chunk = t >> 6;
  float s = 0.f, q = 0.f;
  for (int p2 = chunk * 16; p2 < chunk * 16 + 16; ++p2) {
    s += SPp[((size_t)p2 * N_GRAPHS + g) * 64 + c];
    q += SQp[((size_t)p2 * N_GRAPHS + g) * 64 + c];
  }
  __shared__ float ls[4][64];
  __shared__ float lq[4][64];
  ls[chunk][c] = s;
  lq[chunk][c] = q;
  __syncthreads();
  if (t < 64) {
    s = ls[0][t] + ls[1][t] + ls[2][t] + ls[3][t];
    q = lq[0][t] + lq[1][t] + lq[2][t] + lq[3][t];
    float cnt = fmaxf((float)(gstart[g + 1] - gstart[g]), 1.0f);
    float mean = s / cnt;
    float mm = mean * ms[t];
    float var = q / cnt - 2.f * mm * mean + mm * mm;
    MM[g * 64 + t] = mm;
    IS[g * 64 + t] = rsqrtf(fmaxf(var, 0.f) + EPSN);
  }
  __syncthreads();
  for (int p2 = chunk * 16; p2 < chunk * 16 + 16; ++p2) {
    SPp[((size_t)p2 * N_GRAPHS + g) * 64 + c] = 0.f;
    SQp[((size_t)p2 * N_GRAPHS + g) * 64 + c] = 0.f;
  }
}

// ---------------- fused: GraphNorm + residual + NEXT layer's GEMM + logits ----------------
__global__ __launch_bounds__(256) void k_norm_gemm(
    const u16* __restrict__ Fb, const int* __restrict__ batch,
    const float* __restrict__ MM, const float* __restrict__ IS,
    const float* __restrict__ w, const float* __restrict__ b,
    const u16* __restrict__ Wswz, const float* __restrict__ a_src,
    const float* __restrict__ a_dst, float* __restrict__ X, int residual,
    u8* __restrict__ T8, float* __restrict__ ES, float* __restrict__ ED) {
  __shared__ __align__(16) u16 sY[16][72];   // 144B rows: 16B-aligned
  const int tid = threadIdx.x;
  const long n0 = (long)blockIdx.x * 16;
  {
    const int node = tid >> 4;
    const int c4 = (tid & 15) << 2;
    const long n = n0 + node;
    const int g = batch[n];
    ushort4 fu = *(const ushort4*)(Fb + n * 64 + c4);
    float4 f = make_float4(bf2f(fu.x), bf2f(fu.y), bf2f(fu.z), bf2f(fu.w));
    float4 mm = *(const float4*)(MM + g * 64 + c4);
    float4 is = *(const float4*)(IS + g * 64 + c4);
    float4 wv = *(const float4*)(w + c4);
    float4 bv = *(const float4*)(b + c4);
    float4 y;
    y.x = fmaf(wv.x * (f.x - mm.x), is.x, bv.x);
    y.y = fmaf(wv.y * (f.y - mm.y), is.y, bv.y);
    y.z = fmaf(wv.z * (f.z - mm.z), is.z, bv.z);
    y.w = fmaf(wv.w * (f.w - mm.w), is.w, bv.w);
    float4* xp = (float4*)(X + n * 64 + c4);
    if (residual) {
      float4 xo = *xp;
      y.x += xo.x; y.y += xo.y; y.z += xo.z; y.w += xo.w;
    }
    *xp = y;
    union { u16 s[4]; unsigned long long ll; } pk;
    pk.s[0] = f2bf(y.x); pk.s[1] = f2bf(y.y); pk.s[2] = f2bf(y.z); pk.s[3] = f2bf(y.w);
    *(unsigned long long*)&sY[node][c4] = pk.ll;
  }
  __syncthreads();
  const int lane = tid & 63;
  const int wid = tid >> 6;
  const int grp = lane >> 4, n16 = lane & 15;
  bf16x8 afr[2];
  #pragma unroll
  for (int ks = 0; ks < 2; ++ks)
    afr[ks] = *(const bf16x8*)(&sY[n16][ks * 32 + grp * 8]);
  f32x4 a = {0.f, 0.f, 0.f, 0.f};
  #pragma unroll
  for (int ks = 0; ks < 2; ++ks) {
    bf16x8 bb = *(const bf16x8*)(Wswz + ((size_t)(wid * 2 + ks) * 64 + lane) * 8);
    a = __builtin_amdgcn_mfma_f32_16x16x32_bf16(afr[ks], bb, a, 0, 0, 0);
  }
  const float as_c = a_src[wid * 16 + n16];
  const float ad_c = a_dst[wid * 16 + n16];
  #pragma unroll
  for (int r = 0; r < 4; ++r) {
    const long row = n0 + grp * 4 + r;
    float v = a[r];
    T8[row * 64 + wid * 16 + n16] = f2fp8(v);
    float s = v * as_c;
    float d = v * ad_c;
    s += __shfl_xor(s, 1); s += __shfl_xor(s, 2); s += __shfl_xor(s, 4); s += __shfl_xor(s, 8);
    d += __shfl_xor(d, 1); d += __shfl_xor(d, 2); d += __shfl_xor(d, 4); d += __shfl_xor(d, 8);
    if (n16 == 0) {
      ES[row * 4 + wid] = s;
      ED[row * 4 + wid] = d;
    }
  }
}

// ---------------- last layer: plain norm + residual ----------------
__global__ void k_norm_res(const u16* __restrict__ Fb, const int* __restrict__ batch,
                           const float* __restrict__ MM, const float* __restrict__ IS,
                           const float* __restrict__ w, const float* __restrict__ b,
                           float* __restrict__ X) {
  const long i4 = (long)blockIdx.x * 256 + threadIdx.x;
  const int n = (int)(i4 >> 4);
  const int c4 = (int)(i4 & 15) << 2;
  const int g = batch[n];
  ushort4 fu = *(const ushort4*)(Fb + i4 * 4);
  float4 f = make_float4(bf2f(fu.x), bf2f(fu.y), bf2f(fu.z), bf2f(fu.w));
  float4 mm = *(const float4*)(MM + g * 64 + c4);
  float4 is = *(const float4*)(IS + g * 64 + c4);
  float4 wv = *(const float4*)(w + c4);
  float4 bv = *(const float4*)(b + c4);
  float4 y;
  y.x = fmaf(wv.x * (f.x - mm.x), is.x, bv.x);
  y.y = fmaf(wv.y * (f.y - mm.y), is.y, bv.y);
  y.z = fmaf(wv.z * (f.z - mm.z), is.z, bv.z);
  y.w = fmaf(wv.w * (f.w - mm.w), is.w, bv.w);
  float4* xp = (float4*)(X + i4 * 4);
  float4 xo = *xp;
  y.x += xo.x; y.y += xo.y; y.z += xo.z; y.w += xo.w;
  *xp = y;
}

// ---------------- final pooling moments (fp32 X, 16 partials) ----------------
__global__ void k_moments_final(const float* __restrict__ X, const int* __restrict__ gstart,
                                float* __restrict__ SP) {
  const int g = blockIdx.x;
  const int s0 = gstart[g];
  const int rows = gstart[g + 1] - s0;
  const int lane = threadIdx.x & 63;
  const int w = threadIdx.x >> 6;
  float sum = 0.f;
  for (int r = blockIdx.y * 4 + w; r < rows; r += gridDim.y * 4)
    sum += X[(long)(s0 + r) * 64 + lane];
  __shared__ float ls[4][64];
  ls[w][lane] = sum;
  __syncthreads();
  if (threadIdx.x < 64) {
    float a = ls[0][lane] + ls[1][lane] + ls[2][lane] + ls[3][lane];
    SP[(blockIdx.y * N_GRAPHS + g) * 64 + lane] = a;
  }
}

// ---------------- pooled MLP head (one block) ----------------
__global__ __launch_bounds__(512) void k_mlp(
    const float* __restrict__ SP, const int* __restrict__ gstart, const float* __restrict__ gf,
    const float* __restrict__ W0, const float* __restrict__ b0,
    const float* __restrict__ lw0, const float* __restrict__ lb0,
    const float* __restrict__ Wg, const float* __restrict__ bg,
    const float* __restrict__ lwg, const float* __restrict__ lbg,
    const float* __restrict__ hW, const float* __restrict__ hb,
    float* __restrict__ out) {
  __shared__ float P[16][88];
  __shared__ float Z[16][32];
  const int tid = threadIdx.x;
  for (int i = tid; i < 16 * 88; i += 512) {
    int g = i / 88, c = i - g * 88;
    float v;
    if (c < 64) {
      float s = 0.f;
      #pragma unroll
      for (int b = 0; b < NPART; ++b) s += SP[(b * N_GRAPHS + g) * 64 + c];
      float cnt = fmaxf((float)(gstart[g + 1] - gstart[g]), 1.0f);
      v = s / cnt;
    } else {
      v = gf[g * GDIM + (c - 64)];
    }
    P[g][c] = v;
  }
  __syncthreads();
  const int g = tid >> 5, c = tid & 31;
  float acc = b0[c];
  for (int k = 0; k < 88; ++k) acc = fmaf(P[g][k], W0[k * 32 + c], acc);
  float z = ln32(gelu_exact(acc), lw0[c], lb0[c]);
  for (int l = 0; l < LL; ++l) {
    Z[g][c] = z;
    __syncthreads();
    float a2 = bg[l * 32 + c];
    const float* Wl = Wg + l * 32 * 32;
    for (int k = 0; k < 32; ++k) a2 = fmaf(Z[g][k], Wl[k * 32 + c], a2);
    __syncthreads();
    z = ln32(gelu_exact(a2), lwg[l * 32 + c], lbg[l * 32 + c]) + z;
  }
  Z[g][c] = z * hW[c];
  __syncthreads();
  if (c == 0) {
    float s = 0.f;
    for (int k = 0; k < 32; ++k) s += Z[g][k];
    out[g] = s + hb[0];
  }
}

extern "C" void kernel_launch(void* const* d_in, const int* in_sizes, int n_in,
                              void* d_out, int out_size, void* d_ws, size_t ws_size,
                              hipStream_t stream) {
  const float* x   = (const float*)d_in[0];
  const int*   ei  = (const int*)d_in[1];
  const int* batch = (const int*)d_in[2];
  const float* gf  = (const float*)d_in[3];
  const float* W0  = (const float*)d_in[4];
  const float* as0 = (const float*)d_in[5];
  const float* ad0 = (const float*)d_in[6];
  const float* b0  = (const float*)d_in[7];
  const float* gw0 = (const float*)d_in[8];
  const float* gb0 = (const float*)d_in[9];
  const float* gm0 = (const float*)d_in[10];
  const float* Wg  = (const float*)d_in[11];
  const float* asg = (const float*)d_in[12];
  const float* adg = (const float*)d_in[13];
  const float* bg  = (const float*)d_in[14];
  const float* gwg = (const float*)d_in[15];
  const float* gbg = (const float*)d_in[16];
  const float* gmg = (const float*)d_in[17];
  const float* mW0 = (const float*)d_in[18];
  const float* mb0 = (const float*)d_in[19];
  const float* lw0 = (const float*)d_in[20];
  const float* lb0 = (const float*)d_in[21];
  const float* mWg = (const float*)d_in[22];
  const float* mbg = (const float*)d_in[23];
  const float* lwg = (const float*)d_in[24];
  const float* lbg = (const float*)d_in[25];
  const float* hW  = (const float*)d_in[26];
  const float* hb  = (const float*)d_in[27];
  float* out = (float*)d_out;
  const int* src = ei;
  const int* dst = ei + N_EDGES;

  char* p = (char*)d_ws;
  auto alloc = [&](size_t bytes) {
    char* r = p;
    p += (bytes + 255) & ~(size_t)255;
    return (void*)r;
  };
  float* X   = (float*)alloc((size_t)N_NODES * 64 * 4);
  u16*   Fb  = (u16*)alloc((size_t)N_NODES * 64 * 2);
  u8*    T8  = (u8*)alloc((size_t)N_NODES * 64);
  float* ES  = (float*)alloc((size_t)N_NODES * 4 * 4);
  float* ED  = (float*)alloc((size_t)N_NODES * 4 * 4);
  int* ssrc  = (int*)alloc((size_t)N_EDGES * 4);
  int* deg   = (int*)alloc((size_t)N_NODES * 4);
  int* off   = (int*)alloc((size_t)(N_NODES + 1) * 4);
  int* cur   = (int*)alloc((size_t)N_NODES * 4);
  int* bsum  = (int*)alloc(4096);
  int* gstart = (int*)alloc((N_GRAPHS + 1) * 4);
  u16* W0s   = (u16*)alloc((size_t)W0S_ELEMS * 2);
  u16* Wgs   = (u16*)alloc((size_t)GL * WGS_ELEMS * 2);
  float* SPp = (float*)alloc((size_t)MPART * N_GRAPHS * 64 * 4);
  float* SQp = (float*)alloc((size_t)MPART * N_GRAPHS * 64 * 4);
  float* SP  = (float*)alloc(NPART * N_GRAPHS * 64 * 4);
  float* MM  = (float*)alloc(N_GRAPHS * 64 * 4);
  float* IS  = (float*)alloc(N_GRAPHS * 64 * 4);
  (void)ws_size; (void)in_sizes; (void)n_in; (void)out_size;

  const int NB = (N_NODES + 255) / 256;
  hipMemsetAsync(deg, 0, (size_t)N_NODES * 4, stream);
  hipMemsetAsync(SPp, 0, (size_t)MPART * N_GRAPHS * 64 * 4 * 2, stream);  // SPp+SQp contiguous
  k_count_part<<<2048, 256, 0, stream>>>(dst, deg);
  k_block_sums<<<NB, 256, 0, stream>>>(deg, bsum);
  k_scan_bsums<<<1, 512, 0, stream>>>(bsum, NB, off);
  k_scan_final<<<NB, 256, 0, stream>>>(deg, bsum, off, cur);
  k_scatter_part<<<2048, 256, 0, stream>>>(src, dst, cur, ssrc);
  k_graph_starts<<<1, 32, 0, stream>>>(batch, gstart);
  k_prep_w<<<(W0S_ELEMS + GL * WGS_ELEMS + 255) / 256, 256, 0, stream>>>(W0, Wg, W0s, Wgs);

  const int GG = (N_NODES / 16 + 3) / 4;
  k_gemm0<<<GG, 256, 0, stream>>>(x, W0s, as0, ad0, T8, ES, ED);
  for (int l = 0; l < 1 + GL; ++l) {
    const float* bl  = (l == 0) ? b0  : (bg  + (size_t)(l - 1) * 64);
    const float* gwl = (l == 0) ? gw0 : (gwg + (size_t)(l - 1) * 64);
    const float* gbl = (l == 0) ? gb0 : (gbg + (size_t)(l - 1) * 64);
    const float* gml = (l == 0) ? gm0 : (gmg + (size_t)(l - 1) * 64);
    k_edge_agg<<<EBLK, 256, 0, stream>>>(T8, ES, ED, off, ssrc, bl, batch, Fb, SPp, SQp);
    k_stats<<<N_GRAPHS, 256, 0, stream>>>(gstart, gml, SPp, SQp, MM, IS);
    if (l < GL) {
      k_norm_gemm<<<N_NODES / 16, 256, 0, stream>>>(
          Fb, batch, MM, IS, gwl, gbl,
          Wgs + (size_t)l * WGS_ELEMS, asg + (size_t)l * 64, adg + (size_t)l * 64,
          X, (l > 0) ? 1 : 0, T8, ES, ED);
    } else {
      k_norm_res<<<(N_NODES * 64) / 1024, 256, 0, stream>>>(Fb, batch, MM, IS, gwl, gbl, X);
    }
  }

  k_moments_final<<<dim3(N_GRAPHS, NPART), 256, 0, stream>>>(X, gstart, SP);
  k_mlp<<<1, 512, 0, stream>>>(SP, gstart, gf, mW0, mb0, lw0, lb0,
                               mWg, mbg, lwg, lbg, hW, hb, out);
}